// Round 7
// baseline (4040.154 us; speedup 1.0000x reference)
//
#include <hip/hip_runtime.h>

#define D 1024
#define G3 3072
#define NV 50257
#define NU 1024
#define KU 256
#define TOKROWS 4096
#define SCL 256.0f
#define ISCL2 (1.0f / 65536.0f)
#define ISCL4 (1.0f / 4294967296.0f)

typedef __attribute__((ext_vector_type(8))) _Float16 half8;
typedef __attribute__((ext_vector_type(4))) _Float16 half4;
typedef __attribute__((ext_vector_type(4))) float f32x4;
typedef __attribute__((ext_vector_type(4))) unsigned u32x4;

#define GLDS16(gp, lp) __builtin_amdgcn_global_load_lds( \
    (const __attribute__((address_space(1))) void*)(const void*)(gp), \
    (__attribute__((address_space(3))) void*)(void*)(lp), 16, 0, 0)

static __device__ __forceinline__ float sigmoidf_(float x) {
  return 1.0f / (1.0f + __expf(-x));
}
static __device__ __forceinline__ float tanhf_(float x) {
  float e = __expf(2.0f * x);
  return 1.0f - 2.0f / (e + 1.0f);
}

// Stage 0: gather x and convert W_ih to scaled hi/lo f16 pairs
__global__ __launch_bounds__(256) void k_prep(
    const int* __restrict__ ids, const float* __restrict__ emb,
    const float* __restrict__ Wih,
    _Float16* __restrict__ xh, _Float16* __restrict__ xl,
    _Float16* __restrict__ wh, _Float16* __restrict__ wl)
{
  int t = threadIdx.x;
  int wg = blockIdx.x;
  const float* src;
  _Float16 *dh, *dl;
  if (wg < TOKROWS) {
    src = emb + (size_t)ids[wg] * D;
    dh = xh + (size_t)wg * D; dl = xl + (size_t)wg * D;
  } else {
    int r = wg - TOKROWS;
    src = Wih + (size_t)r * D;
    dh = wh + (size_t)r * D; dl = wl + (size_t)r * D;
  }
  f32x4 v = ((const f32x4*)src)[t];
  half4 h, l;
#pragma unroll
  for (int j = 0; j < 4; ++j) {
    float vs = v[j] * SCL;
    _Float16 hi = (_Float16)vs;
    h[j] = hi;
    l[j] = (_Float16)(vs - (float)hi);
  }
  *(half4*)(dh + t * 4) = h;
  *(half4*)(dl + t * 4) = l;
}

// Stage 1: gi = x @ W_ih^T + b_ih  (split-f16 MFMA, f32 out)
__global__ __launch_bounds__(256) void k_gi(
    const _Float16* __restrict__ Ah, const _Float16* __restrict__ Al,
    const _Float16* __restrict__ Bh, const _Float16* __restrict__ Bl,
    const float* __restrict__ bih, float* __restrict__ gi)
{
  __shared__ _Float16 Ash[128 * 32];
  __shared__ _Float16 Asl[128 * 32];
  __shared__ _Float16 Bsh[128 * 32];
  __shared__ _Float16 Bsl[128 * 32];
  int tid = threadIdx.x;
  int bm = blockIdx.x, bn = blockIdx.y;
  int lane = tid & 63, w = tid >> 6;
  int nl = lane & 15, q = lane >> 4;
  int wr = w >> 1, wc = w & 1;
  f32x4 zero = {0.f, 0.f, 0.f, 0.f};
  f32x4 acc[4][4];
#pragma unroll
  for (int i = 0; i < 4; i++)
#pragma unroll
    for (int j = 0; j < 4; j++) acc[i][j] = zero;
  int r0 = tid >> 2;
  int c0 = (tid & 3) * 8;
  int wb = w * 512;  // wave-uniform LDS staging base (16 rows x 32)
  for (int kc = 0; kc < 32; ++kc) {
    __syncthreads();
    size_t go = ((size_t)(bm * 128 + r0)) * D + kc * 32 + c0;
    size_t go2 = ((size_t)(bn * 128 + r0)) * D + kc * 32 + c0;
    GLDS16(Ah + go, Ash + wb);
    GLDS16(Ah + go + 64 * D, Ash + wb + 2048);
    GLDS16(Al + go, Asl + wb);
    GLDS16(Al + go + 64 * D, Asl + wb + 2048);
    GLDS16(Bh + go2, Bsh + wb);
    GLDS16(Bh + go2 + 64 * D, Bsh + wb + 2048);
    GLDS16(Bl + go2, Bsl + wb);
    GLDS16(Bl + go2 + 64 * D, Bsl + wb + 2048);
    __syncthreads();
    half8 afh[4], afl[4], bfh[4], bfl[4];
#pragma unroll
    for (int mt = 0; mt < 4; ++mt) {
      int o = (wr * 64 + mt * 16 + nl) * 32 + q * 8;
      afh[mt] = *(const half8*)(Ash + o);
      afl[mt] = *(const half8*)(Asl + o);
    }
#pragma unroll
    for (int nt = 0; nt < 4; ++nt) {
      int o = (wc * 64 + nt * 16 + nl) * 32 + q * 8;
      bfh[nt] = *(const half8*)(Bsh + o);
      bfl[nt] = *(const half8*)(Bsl + o);
    }
#pragma unroll
    for (int mt = 0; mt < 4; ++mt)
#pragma unroll
      for (int nt = 0; nt < 4; ++nt) {
        acc[mt][nt] = __builtin_amdgcn_mfma_f32_16x16x32_f16(afh[mt], bfh[nt], acc[mt][nt], 0, 0, 0);
        acc[mt][nt] = __builtin_amdgcn_mfma_f32_16x16x32_f16(afh[mt], bfl[nt], acc[mt][nt], 0, 0, 0);
        acc[mt][nt] = __builtin_amdgcn_mfma_f32_16x16x32_f16(afl[mt], bfh[nt], acc[mt][nt], 0, 0, 0);
      }
  }
#pragma unroll
  for (int mt = 0; mt < 4; ++mt)
#pragma unroll
    for (int nt = 0; nt < 4; ++nt) {
      int col = bn * 128 + wc * 64 + nt * 16 + nl;
      float bv = bih[col];
#pragma unroll
      for (int i = 0; i < 4; i++) {
        int row = bm * 128 + wr * 64 + mt * 16 + q * 4 + i;
        gi[(size_t)row * G3 + col] = acc[mt][nt][i] * ISCL2 + bv;
      }
    }
}

// init: zero the h-record double buffer (2 x 4096 records x 16B); tags become 0,
// which is exactly what step 0 polls for (h(0)=0). Must run every launch (replay).
__global__ void k_init(unsigned* __restrict__ rec32)
{
  int t = threadIdx.x;
  for (int i = t; i < 32768; i += 256) rec32[i] = 0u;
}

// Stage 2: GRU scan, 64 WGs x 6 waves. h exchanged as 16B records
// {pkh, pkl, tag, pad}; the tag rides with the data (dataflow barrier, exact-tag
// match is skew-safe). Two-phase poll: cheap sentinel spin (1 record/producer-WG
// per lane, ~1KB/wave/round) to avoid L3 bandwidth congestion, then ONE bulk
// load + tag-verify round for the payload.
__global__ __launch_bounds__(384) void k_gru(
    const float* __restrict__ Whh, const float* __restrict__ gi,
    const float* __restrict__ bhh, unsigned* __restrict__ hrec,
    float* __restrict__ ctx)
{
  int tid = threadIdx.x;
  int wid = blockIdx.x;           // 64 WGs, d-slice of 16 each
  int w = tid >> 6;               // 6 waves
  int g = w >> 1;                 // gate: 0=r 1=z 2=n
  int kh = w & 1;                 // K half (512 each)
  int lane = tid & 63, nl = lane & 15, q = lane >> 4;
  __shared__ _Float16 hs[16 * 1024];   // unpacked h (32 KB), 16B-chunk XOR swizzle
  __shared__ float gp[6][3][8][17];    // [wave][slot][batch][d] partials

  // W_hh slice -> registers, scaled hi/lo f16 B-fragments
  half8 bwh[16], bwl[16];
  {
    const float* wrow = Whh + ((size_t)(g * 1024 + wid * 16 + nl)) * D + kh * 512;
#pragma unroll
    for (int kt = 0; kt < 16; ++kt) {
      const f32x4* p = (const f32x4*)(wrow + kt * 32 + q * 8);
      f32x4 v0 = p[0], v1 = p[1];
      half8 h, l;
#pragma unroll
      for (int j = 0; j < 4; ++j) {
        float s0 = v0[j] * SCL;
        _Float16 h0 = (_Float16)s0;
        h[j] = h0; l[j] = (_Float16)(s0 - (float)h0);
        float s1 = v1[j] * SCL;
        _Float16 h1 = (_Float16)s1;
        h[j + 4] = h1; l[j + 4] = (_Float16)(s1 - (float)h1);
      }
      bwh[kt] = h; bwl[kt] = l;
    }
  }

  // update-role state (wave 0): each thread owns (batch m, dims d0,d0+1)
  int m = tid >> 3, np = (tid & 7) * 2;
  int d0 = wid * 16 + np;
  float hr0 = 0.f, hr1 = 0.f;
  float bh[6] = {0, 0, 0, 0, 0, 0};
  if (tid < 64) {
#pragma unroll
    for (int gg = 0; gg < 3; ++gg) {
      bh[gg * 2] = bhh[gg * 1024 + d0];
      bh[gg * 2 + 1] = bhh[gg * 1024 + d0 + 1];
    }
  }
  f32x4 zero = {0, 0, 0, 0};

  for (int step = 0; step < 512; ++step) {
    float gi6[6] = {0, 0, 0, 0, 0, 0};
    if (tid < 64) {  // gi for this step (f32, plain cached loads; drain in poll)
      const float* gpt = gi + ((size_t)(m * 512 + step)) * G3 + d0;
#pragma unroll
      for (int gg = 0; gg < 3; ++gg) {
        gi6[gg * 2] = gpt[gg * 1024];
        gi6[gg * 2 + 1] = gpt[gg * 1024 + 1];
      }
    }

    // ---- dataflow barrier: sentinel spin, then bulk load + verify ----
    {
      unsigned want = (unsigned)step;
      const u32x4* rb = (const u32x4*)hrec + (size_t)(step & 1) * 4096;
      // phase 1: lane spins on producer-WG[lane]'s record 0 (16B, low L3 traffic)
      {
        const u32x4* sent = rb + (size_t)lane * 64;
        u32x4 sv;
        do {
          asm volatile("global_load_dwordx4 %0, %1, off sc0 sc1\n\ts_waitcnt vmcnt(0)"
                       : "=v"(sv) : "v"(sent) : "memory");
        } while (!__all((int)(sv[2] == want)));
      }
      // phase 2: bulk load all records once; tag-verify catches visibility skew
      u32x4 rv[11];
      unsigned need = 0;
#pragma unroll
      for (int k = 0; k < 11; ++k) {
        int r = tid + k * 384;
        if (r < 4096) need |= (1u << k);
      }
      while (need) {
        unsigned mm = need;
#pragma unroll
        for (int k = 0; k < 11; ++k)
          if (mm & (1u << k)) {
            int r = tid + k * 384;
            asm volatile("global_load_dwordx4 %0, %1, off sc0 sc1"
                         : "=v"(rv[k]) : "v"(rb + r));
          }
        asm volatile("s_waitcnt vmcnt(0)" ::: "memory");
#pragma unroll
        for (int k = 0; k < 11; ++k)
          if ((mm & (1u << k)) && rv[k][2] == want) need &= ~(1u << k);
      }
      __builtin_amdgcn_sched_barrier(0);
#pragma unroll
      for (int k = 0; k < 11; ++k) {
        int r = tid + k * 384;
        if (r < 4096) {
          int w2 = r >> 6, l2 = r & 63;
          int m2 = l2 >> 3;
          int d = (w2 << 4) + ((l2 & 7) << 1);
          int chunk = d >> 3, wi = d & 7;
          int sw = chunk ^ (m2 & 7);
          *(unsigned*)&hs[((m2 * 128 + sw) << 3) + wi] = rv[k][0];          // hi row
          *(unsigned*)&hs[(((m2 + 8) * 128 + sw) << 3) + wi] = rv[k][1];    // lo row
        }
      }
    }
    __syncthreads();  // #A: staged h visible

    // A fragments from LDS (swizzled chunks), then MFMA (4 independent chains)
    half8 av[16];
#pragma unroll
    for (int kt = 0; kt < 16; ++kt) {
      int chunk = kh * 64 + kt * 4 + q;
      av[kt] = *(const half8*)&hs[(size_t)(nl * 128 + (chunk ^ (nl & 7))) * 8];
    }
    f32x4 a1e = zero, a1o = zero, a2e = zero, a2o = zero;
#pragma unroll
    for (int kt = 0; kt < 16; kt += 2) {
      a1e = __builtin_amdgcn_mfma_f32_16x16x32_f16(av[kt], bwh[kt], a1e, 0, 0, 0);
      a2e = __builtin_amdgcn_mfma_f32_16x16x32_f16(av[kt], bwl[kt], a2e, 0, 0, 0);
      a1o = __builtin_amdgcn_mfma_f32_16x16x32_f16(av[kt + 1], bwh[kt + 1], a1o, 0, 0, 0);
      a2o = __builtin_amdgcn_mfma_f32_16x16x32_f16(av[kt + 1], bwl[kt + 1], a2o, 0, 0, 0);
    }
    f32x4 ac1 = a1e + a1o;
    f32x4 ac2 = a2e + a2o;
    // partials: slot0 = hi@Wh (rows 0-7), slot1 = lo@Wh (rows 8-15), slot2 = hi@Wl
    if (q < 2) {
#pragma unroll
      for (int i = 0; i < 4; i++) {
        gp[w][0][q * 4 + i][nl] = ac1[i];
        gp[w][2][q * 4 + i][nl] = ac2[i];
      }
    } else {
#pragma unroll
      for (int i = 0; i < 4; i++) gp[w][1][(q - 2) * 4 + i][nl] = ac1[i];
    }
    __syncthreads();  // #B: partials visible to wave 0
    if (tid < 64) {
      float gh[6];
#pragma unroll
      for (int g2 = 0; g2 < 3; ++g2) {
        float s0 = 0.f, s1 = 0.f;
#pragma unroll
        for (int k2 = 0; k2 < 2; ++k2) {
          int wv = g2 * 2 + k2;
#pragma unroll
          for (int s = 0; s < 3; ++s) {
            s0 += gp[wv][s][m][np];
            s1 += gp[wv][s][m][np + 1];
          }
        }
        gh[g2 * 2] = s0 * ISCL2;
        gh[g2 * 2 + 1] = s1 * ISCL2;
      }
      float r0_ = sigmoidf_(gi6[0] + gh[0] + bh[0]);
      float r1_ = sigmoidf_(gi6[1] + gh[1] + bh[1]);
      float z0_ = sigmoidf_(gi6[2] + gh[2] + bh[2]);
      float z1_ = sigmoidf_(gi6[3] + gh[3] + bh[3]);
      float n0_ = tanhf_(gi6[4] + r0_ * (gh[4] + bh[4]));
      float n1_ = tanhf_(gi6[5] + r1_ * (gh[5] + bh[5]));
      float h0_ = (1.f - z0_) * n0_ + z0_ * hr0;
      float h1_ = (1.f - z1_) * n1_ + z1_ * hr1;
      hr0 = h0_; hr1 = h1_;
      float s0 = h0_ * SCL, s1 = h1_ * SCL;
      _Float16 h0h = (_Float16)s0, h1h = (_Float16)s1;
      _Float16 h0l = (_Float16)(s0 - (float)h0h), h1l = (_Float16)(s1 - (float)h1h);
      u32x4 rec;
      rec[0] = (unsigned)__builtin_bit_cast(unsigned short, h0h) |
               ((unsigned)__builtin_bit_cast(unsigned short, h1h) << 16);
      rec[1] = (unsigned)__builtin_bit_cast(unsigned short, h0l) |
               ((unsigned)__builtin_bit_cast(unsigned short, h1l) << 16);
      rec[2] = (unsigned)(step + 1);
      rec[3] = 0u;
      u32x4* dst = (u32x4*)hrec + ((size_t)((step + 1) & 1) * 4096 + wid * 64 + tid);
      asm volatile("global_store_dwordx4 %0, %1, off sc0 sc1"
                   :: "v"(dst), "v"(rec) : "memory");
      if (step == 511) {
        ctx[m * D + d0] = h0_;
        ctx[m * D + d0 + 1] = h1_;
      }
    }
    // no third barrier: next step's poll is the dataflow barrier
  }
}

// Stage 3: U = ctx @ W_A^T + b_A  (f32 VALU, BW-bound); scaled hi/lo out
__global__ __launch_bounds__(256) void k_u(
    const float* __restrict__ WA, const float* __restrict__ bA,
    const float* __restrict__ ctx, _Float16* __restrict__ Uth,
    _Float16* __restrict__ Utl)
{
  __shared__ float As[128 * 32];
  __shared__ float cx[8][1032];
  int tid = threadIdx.x;
  int RB = blockIdx.x;  // 2048 blocks x 128 rows
#pragma unroll
  for (int jj = 0; jj < 8; ++jj) {
    int e = tid * 32 + jj * 4;
    *(f32x4*)&cx[e >> 10][e & 1023] = *(const f32x4*)(ctx + e);
  }
  float acc[4] = {0.f, 0.f, 0.f, 0.f};
  int b = tid & 7, rq = tid >> 3;
  float* AsW = As + (tid >> 6) * 256;  // wave-uniform staging base (1KB)
  int sr = tid >> 3;
  int sc = (tid & 7) * 4;
  __syncthreads();
  for (int kc = 0; kc < 32; ++kc) {
    __syncthreads();
    const float* gsrc = WA + ((size_t)(RB * 128 + sr)) * D + kc * 32 + sc;
    GLDS16(gsrc, AsW);
    GLDS16(gsrc + 32 * D, AsW + 1024);
    GLDS16(gsrc + 64 * D, AsW + 2048);
    GLDS16(gsrc + 96 * D, AsW + 3072);
    __syncthreads();
    f32x4 cxr[8];
#pragma unroll
    for (int kk = 0; kk < 8; ++kk) cxr[kk] = *(const f32x4*)&cx[b][kc * 32 + kk * 4];
#pragma unroll
    for (int r = 0; r < 4; ++r) {
      const float* ap = As + (rq * 4 + r) * 32;
      float s = 0.f;
#pragma unroll
      for (int kk = 0; kk < 8; ++kk) {
        f32x4 a = *(const f32x4*)(ap + kk * 4);
        f32x4 c = cxr[kk];
        s += a[0] * c[0] + a[1] * c[1] + a[2] * c[2] + a[3] * c[3];
      }
      acc[r] += s;
    }
  }
#pragma unroll
  for (int r = 0; r < 4; ++r) {
    int R = RB * 128 + rq * 4 + r;
    float v = (acc[r] + bA[R]) * SCL;
    int n_u = R >> 8, k_u = R & 255;
    _Float16 hi = (_Float16)v;
    size_t o = ((size_t)(b * 256 + k_u)) * NU + n_u;  // k-major for stage-4 frags
    Uth[o] = hi;
    Utl[o] = (_Float16)(v - (float)hi);
  }
}

// Stage 4: logits[b][v] = sum_k (sum_n eg[v][n] U[b][n][k])^2  (split-f16)
__global__ __launch_bounds__(256, 2) void k_logits(
    const float* __restrict__ eg, const _Float16* __restrict__ Uth,
    const _Float16* __restrict__ Utl, float* __restrict__ out)
{
  __shared__ _Float16 Ash[64 * 40];  // 64 v-rows x 32 n (padded)
  __shared__ _Float16 Asl[64 * 40];
  __shared__ float lacc[8][64];
  int tid = threadIdx.x;
  int v0 = blockIdx.x * 64;
  int lane = tid & 63, w = tid >> 6, nl = lane & 15, q = lane >> 4;
  for (int i = tid; i < 512; i += 256) ((float*)lacc)[i] = 0.f;
  int sr = tid >> 2;
  int sc = (tid & 3) * 8;
  int vr = v0 + sr;
  if (vr >= NV) vr = NV - 1;
  const float* asrc = eg + (size_t)vr * NU;
  f32x4 zero = {0, 0, 0, 0};
  __syncthreads();
  for (int kg = 0; kg < 4; ++kg) {
    f32x4 acc[8][4];
#pragma unroll
    for (int b = 0; b < 8; ++b)
#pragma unroll
      for (int mt = 0; mt < 4; ++mt) acc[b][mt] = zero;
    for (int nc = 0; nc < 32; ++nc) {
      __syncthreads();
      {
        const f32x4* p = (const f32x4*)(asrc + nc * 32 + sc);
        f32x4 u0 = __builtin_nontemporal_load(p);
        f32x4 u1 = __builtin_nontemporal_load(p + 1);
        half8 h, l;
#pragma unroll
        for (int j = 0; j < 4; ++j) {
          float s0 = u0[j] * SCL;
          _Float16 h0 = (_Float16)s0;
          h[j] = h0; l[j] = (_Float16)(s0 - (float)h0);
          float s1 = u1[j] * SCL;
          _Float16 h1 = (_Float16)s1;
          h[j + 4] = h1; l[j + 4] = (_Float16)(s1 - (float)h1);
        }
        *(half8*)(Ash + sr * 40 + sc) = h;
        *(half8*)(Asl + sr * 40 + sc) = l;
      }
      __syncthreads();
      half8 afh[4], afl[4];
#pragma unroll
      for (int mt = 0; mt < 4; ++mt) {
        afh[mt] = *(const half8*)(Ash + (mt * 16 + nl) * 40 + q * 8);
        afl[mt] = *(const half8*)(Asl + (mt * 16 + nl) * 40 + q * 8);
      }
#pragma unroll
      for (int b = 0; b < 8; ++b) {
        size_t o = ((size_t)(b * 256 + kg * 64 + w * 16 + nl)) * NU + nc * 32 + q * 8;
        half8 bfh = *(const half8*)(Uth + o);
        half8 bfl = *(const half8*)(Utl + o);
#pragma unroll
        for (int mt = 0; mt < 4; ++mt) {
          acc[b][mt] = __builtin_amdgcn_mfma_f32_16x16x32_f16(afh[mt], bfh, acc[b][mt], 0, 0, 0);
          acc[b][mt] = __builtin_amdgcn_mfma_f32_16x16x32_f16(afh[mt], bfl, acc[b][mt], 0, 0, 0);
          acc[b][mt] = __builtin_amdgcn_mfma_f32_16x16x32_f16(afl[mt], bfh, acc[b][mt], 0, 0, 0);
        }
      }
    }
#pragma unroll
    for (int b = 0; b < 8; ++b) {
#pragma unroll
      for (int mt = 0; mt < 4; ++mt) {
#pragma unroll
        for (int i = 0; i < 4; ++i) {
          float s = acc[b][mt][i] * acc[b][mt][i];
          s += __shfl_xor(s, 1);
          s += __shfl_xor(s, 2);
          s += __shfl_xor(s, 4);
          s += __shfl_xor(s, 8);
          if (nl == 0) atomicAdd(&lacc[b][mt * 16 + q * 4 + i], s);
        }
      }
    }
  }
  __syncthreads();
  if (tid < 64) {
    int v = v0 + tid;
    if (v < NV) {
#pragma unroll
      for (int b = 0; b < 8; ++b) out[(size_t)b * NV + v] = lacc[b][tid] * ISCL4;
    }
  }
}

extern "C" void kernel_launch(void* const* d_in, const int* in_sizes, int n_in,
                              void* d_out, int out_size, void* d_ws, size_t ws_size,
                              hipStream_t stream)
{
  (void)in_sizes; (void)n_in; (void)out_size; (void)ws_size;
  const int* ids = (const int*)d_in[0];
  const float* emb = (const float*)d_in[1];
  const float* Wih = (const float*)d_in[2];
  const float* Whh = (const float*)d_in[3];
  const float* bih = (const float*)d_in[4];
  const float* bhh = (const float*)d_in[5];
  const float* WA = (const float*)d_in[6];
  const float* bA = (const float*)d_in[7];
  const float* eg = (const float*)d_in[8];
  float* out = (float*)d_out;

  char* ws = (char*)d_ws;
  size_t off = 0;
  auto take = [&](size_t bytes) -> char* {
    char* p = ws + off;
    off += (bytes + 255) & ~(size_t)255;
    return p;
  };
  float* gi32 = (float*)take((size_t)4096 * 3072 * 4);        // 50.3 MB
  char* xregion = take((size_t)4096 * 1024 * 2 * 2);          // x hi+lo 16.8 MB
  _Float16* xh = (_Float16*)xregion;
  _Float16* xl = xh + (size_t)4096 * 1024;
  _Float16* wh = (_Float16*)take((size_t)3072 * 1024 * 2);
  _Float16* wl = (_Float16*)take((size_t)3072 * 1024 * 2);
  unsigned* hrec = (unsigned*)take((size_t)2 * 4096 * 16);    // h record dbuf 128KB
  float* ctx = (float*)take((size_t)8 * 1024 * 4);
  // Ut aliases the x region (x dead after k_gi; Ut written by k_u afterwards)
  _Float16* Uth = (_Float16*)xregion;
  _Float16* Utl = Uth + (size_t)8 * 256 * 1024;

  k_prep<<<dim3(7168), dim3(256), 0, stream>>>(ids, emb, Wih, xh, xl, wh, wl);
  k_gi<<<dim3(32, 24), dim3(256), 0, stream>>>(xh, xl, wh, wl, bih, gi32);
  k_init<<<dim3(1), dim3(256), 0, stream>>>(hrec);
  k_gru<<<dim3(64), dim3(384), 0, stream>>>(Whh, gi32, bhh, hrec, ctx);
  k_u<<<dim3(2048), dim3(256), 0, stream>>>(WA, bA, ctx, Uth, Utl);
  k_logits<<<dim3(786), dim3(256), 0, stream>>>(eg, Uth, Utl, out);
}

// Round 8
// 3543.044 us; speedup vs baseline: 1.1403x; 1.1403x over previous
//
#include <hip/hip_runtime.h>

#define D 1024
#define G3 3072
#define NV 50257
#define NU 1024
#define KU 256
#define TOKROWS 4096
#define SCL 256.0f
#define ISCL2 (1.0f / 65536.0f)
#define ISCL4 (1.0f / 4294967296.0f)

typedef __attribute__((ext_vector_type(8))) _Float16 half8;
typedef __attribute__((ext_vector_type(4))) _Float16 half4;
typedef __attribute__((ext_vector_type(4))) float f32x4;
typedef __attribute__((ext_vector_type(4))) unsigned u32x4;

#define GLDS16(gp, lp) __builtin_amdgcn_global_load_lds( \
    (const __attribute__((address_space(1))) void*)(const void*)(gp), \
    (__attribute__((address_space(3))) void*)(void*)(lp), 16, 0, 0)

static __device__ __forceinline__ float sigmoidf_(float x) {
  return 1.0f / (1.0f + __expf(-x));
}
static __device__ __forceinline__ float tanhf_(float x) {
  float e = __expf(2.0f * x);
  return 1.0f - 2.0f / (e + 1.0f);
}

// Stage 0: gather x and convert W_ih to scaled hi/lo f16 pairs
__global__ __launch_bounds__(256) void k_prep(
    const int* __restrict__ ids, const float* __restrict__ emb,
    const float* __restrict__ Wih,
    _Float16* __restrict__ xh, _Float16* __restrict__ xl,
    _Float16* __restrict__ wh, _Float16* __restrict__ wl)
{
  int t = threadIdx.x;
  int wg = blockIdx.x;
  const float* src;
  _Float16 *dh, *dl;
  if (wg < TOKROWS) {
    src = emb + (size_t)ids[wg] * D;
    dh = xh + (size_t)wg * D; dl = xl + (size_t)wg * D;
  } else {
    int r = wg - TOKROWS;
    src = Wih + (size_t)r * D;
    dh = wh + (size_t)r * D; dl = wl + (size_t)r * D;
  }
  f32x4 v = ((const f32x4*)src)[t];
  half4 h, l;
#pragma unroll
  for (int j = 0; j < 4; ++j) {
    float vs = v[j] * SCL;
    _Float16 hi = (_Float16)vs;
    h[j] = hi;
    l[j] = (_Float16)(vs - (float)hi);
  }
  *(half4*)(dh + t * 4) = h;
  *(half4*)(dl + t * 4) = l;
}

// Stage 1: gi = x @ W_ih^T + b_ih  (split-f16 MFMA, f32 out)
__global__ __launch_bounds__(256) void k_gi(
    const _Float16* __restrict__ Ah, const _Float16* __restrict__ Al,
    const _Float16* __restrict__ Bh, const _Float16* __restrict__ Bl,
    const float* __restrict__ bih, float* __restrict__ gi)
{
  __shared__ _Float16 Ash[128 * 32];
  __shared__ _Float16 Asl[128 * 32];
  __shared__ _Float16 Bsh[128 * 32];
  __shared__ _Float16 Bsl[128 * 32];
  int tid = threadIdx.x;
  int bm = blockIdx.x, bn = blockIdx.y;
  int lane = tid & 63, w = tid >> 6;
  int nl = lane & 15, q = lane >> 4;
  int wr = w >> 1, wc = w & 1;
  f32x4 zero = {0.f, 0.f, 0.f, 0.f};
  f32x4 acc[4][4];
#pragma unroll
  for (int i = 0; i < 4; i++)
#pragma unroll
    for (int j = 0; j < 4; j++) acc[i][j] = zero;
  int r0 = tid >> 2;
  int c0 = (tid & 3) * 8;
  int wb = w * 512;  // wave-uniform LDS staging base (16 rows x 32)
  for (int kc = 0; kc < 32; ++kc) {
    __syncthreads();
    size_t go = ((size_t)(bm * 128 + r0)) * D + kc * 32 + c0;
    size_t go2 = ((size_t)(bn * 128 + r0)) * D + kc * 32 + c0;
    GLDS16(Ah + go, Ash + wb);
    GLDS16(Ah + go + 64 * D, Ash + wb + 2048);
    GLDS16(Al + go, Asl + wb);
    GLDS16(Al + go + 64 * D, Asl + wb + 2048);
    GLDS16(Bh + go2, Bsh + wb);
    GLDS16(Bh + go2 + 64 * D, Bsh + wb + 2048);
    GLDS16(Bl + go2, Bsl + wb);
    GLDS16(Bl + go2 + 64 * D, Bsl + wb + 2048);
    __syncthreads();
    half8 afh[4], afl[4], bfh[4], bfl[4];
#pragma unroll
    for (int mt = 0; mt < 4; ++mt) {
      int o = (wr * 64 + mt * 16 + nl) * 32 + q * 8;
      afh[mt] = *(const half8*)(Ash + o);
      afl[mt] = *(const half8*)(Asl + o);
    }
#pragma unroll
    for (int nt = 0; nt < 4; ++nt) {
      int o = (wc * 64 + nt * 16 + nl) * 32 + q * 8;
      bfh[nt] = *(const half8*)(Bsh + o);
      bfl[nt] = *(const half8*)(Bsl + o);
    }
#pragma unroll
    for (int mt = 0; mt < 4; ++mt)
#pragma unroll
      for (int nt = 0; nt < 4; ++nt) {
        acc[mt][nt] = __builtin_amdgcn_mfma_f32_16x16x32_f16(afh[mt], bfh[nt], acc[mt][nt], 0, 0, 0);
        acc[mt][nt] = __builtin_amdgcn_mfma_f32_16x16x32_f16(afh[mt], bfl[nt], acc[mt][nt], 0, 0, 0);
        acc[mt][nt] = __builtin_amdgcn_mfma_f32_16x16x32_f16(afl[mt], bfh[nt], acc[mt][nt], 0, 0, 0);
      }
  }
#pragma unroll
  for (int mt = 0; mt < 4; ++mt)
#pragma unroll
    for (int nt = 0; nt < 4; ++nt) {
      int col = bn * 128 + wc * 64 + nt * 16 + nl;
      float bv = bih[col];
#pragma unroll
      for (int i = 0; i < 4; i++) {
        int row = bm * 128 + wr * 64 + mt * 16 + q * 4 + i;
        gi[(size_t)row * G3 + col] = acc[mt][nt][i] * ISCL2 + bv;
      }
    }
}

// init: zero the h-record double buffer (2 x 4096 records x 16B); tags become 0,
// which is exactly what step 0 polls for (h(0)=0). Must run every launch (replay).
__global__ void k_init(unsigned* __restrict__ rec32)
{
  int t = threadIdx.x;
  for (int i = t; i < 32768; i += 256) rec32[i] = 0u;
}

// Stage 2 (R6-proven): GRU scan, 64 WGs x 6 waves. h exchanged as 16B records
// {pkh, pkl, tag, pad}; tag rides with the data (dataflow barrier, exact-tag
// match is skew-safe); bulk load + per-chunk tag-verify retry IS the poll.
__global__ __launch_bounds__(384) void k_gru(
    const float* __restrict__ Whh, const float* __restrict__ gi,
    const float* __restrict__ bhh, unsigned* __restrict__ hrec,
    float* __restrict__ ctx)
{
  int tid = threadIdx.x;
  int wid = blockIdx.x;           // 64 WGs, d-slice of 16 each
  int w = tid >> 6;               // 6 waves
  int g = w >> 1;                 // gate: 0=r 1=z 2=n
  int kh = w & 1;                 // K half (512 each)
  int lane = tid & 63, nl = lane & 15, q = lane >> 4;
  __shared__ _Float16 hs[16 * 1024];   // unpacked h (32 KB), 16B-chunk XOR swizzle
  __shared__ float gp[6][3][8][17];    // [wave][slot][batch][d] partials

  // W_hh slice -> registers, scaled hi/lo f16 B-fragments
  half8 bwh[16], bwl[16];
  {
    const float* wrow = Whh + ((size_t)(g * 1024 + wid * 16 + nl)) * D + kh * 512;
#pragma unroll
    for (int kt = 0; kt < 16; ++kt) {
      const f32x4* p = (const f32x4*)(wrow + kt * 32 + q * 8);
      f32x4 v0 = p[0], v1 = p[1];
      half8 h, l;
#pragma unroll
      for (int j = 0; j < 4; ++j) {
        float s0 = v0[j] * SCL;
        _Float16 h0 = (_Float16)s0;
        h[j] = h0; l[j] = (_Float16)(s0 - (float)h0);
        float s1 = v1[j] * SCL;
        _Float16 h1 = (_Float16)s1;
        h[j + 4] = h1; l[j + 4] = (_Float16)(s1 - (float)h1);
      }
      bwh[kt] = h; bwl[kt] = l;
    }
  }

  // update-role state (wave 0): each thread owns (batch m, dims d0,d0+1)
  int m = tid >> 3, np = (tid & 7) * 2;
  int d0 = wid * 16 + np;
  float hr0 = 0.f, hr1 = 0.f;
  float bh[6] = {0, 0, 0, 0, 0, 0};
  if (tid < 64) {
#pragma unroll
    for (int gg = 0; gg < 3; ++gg) {
      bh[gg * 2] = bhh[gg * 1024 + d0];
      bh[gg * 2 + 1] = bhh[gg * 1024 + d0 + 1];
    }
  }
  f32x4 zero = {0, 0, 0, 0};

  for (int step = 0; step < 512; ++step) {
    float gi6[6] = {0, 0, 0, 0, 0, 0};
    if (tid < 64) {  // gi for this step (f32, plain cached loads; drain in poll)
      const float* gpt = gi + ((size_t)(m * 512 + step)) * G3 + d0;
#pragma unroll
      for (int gg = 0; gg < 3; ++gg) {
        gi6[gg * 2] = gpt[gg * 1024];
        gi6[gg * 2 + 1] = gpt[gg * 1024 + 1];
      }
    }

    // ---- poll h records (tag == step) and unpack into LDS ----
    {
      unsigned want = (unsigned)step;
      const u32x4* rb = (const u32x4*)hrec + (size_t)(step & 1) * 4096;
      u32x4 rv[11];
      unsigned need = 0;
#pragma unroll
      for (int k = 0; k < 11; ++k) {
        int r = tid + k * 384;
        if (r < 4096) need |= (1u << k);
      }
      while (need) {
        unsigned mm = need;
#pragma unroll
        for (int k = 0; k < 11; ++k)
          if (mm & (1u << k)) {
            int r = tid + k * 384;
            asm volatile("global_load_dwordx4 %0, %1, off sc0 sc1"
                         : "=v"(rv[k]) : "v"(rb + r));
          }
        asm volatile("s_waitcnt vmcnt(0)" ::: "memory");
#pragma unroll
        for (int k = 0; k < 11; ++k)
          if ((mm & (1u << k)) && rv[k][2] == want) need &= ~(1u << k);
      }
      __builtin_amdgcn_sched_barrier(0);
#pragma unroll
      for (int k = 0; k < 11; ++k) {
        int r = tid + k * 384;
        if (r < 4096) {
          int w2 = r >> 6, l2 = r & 63;
          int m2 = l2 >> 3;
          int d = (w2 << 4) + ((l2 & 7) << 1);
          int chunk = d >> 3, wi = d & 7;
          int sw = chunk ^ (m2 & 7);
          *(unsigned*)&hs[((m2 * 128 + sw) << 3) + wi] = rv[k][0];          // hi row
          *(unsigned*)&hs[(((m2 + 8) * 128 + sw) << 3) + wi] = rv[k][1];    // lo row
        }
      }
    }
    __syncthreads();  // #A: staged h visible

    // A fragments from LDS (swizzled chunks), then MFMA
    half8 av[16];
#pragma unroll
    for (int kt = 0; kt < 16; ++kt) {
      int chunk = kh * 64 + kt * 4 + q;
      av[kt] = *(const half8*)&hs[(size_t)(nl * 128 + (chunk ^ (nl & 7))) * 8];
    }
    f32x4 ac1 = zero, ac2 = zero;
#pragma unroll
    for (int kt = 0; kt < 16; ++kt) {
      ac1 = __builtin_amdgcn_mfma_f32_16x16x32_f16(av[kt], bwh[kt], ac1, 0, 0, 0);
      ac2 = __builtin_amdgcn_mfma_f32_16x16x32_f16(av[kt], bwl[kt], ac2, 0, 0, 0);
    }
    // partials: slot0 = hi@Wh (rows 0-7), slot1 = lo@Wh (rows 8-15), slot2 = hi@Wl
    if (q < 2) {
#pragma unroll
      for (int i = 0; i < 4; i++) {
        gp[w][0][q * 4 + i][nl] = ac1[i];
        gp[w][2][q * 4 + i][nl] = ac2[i];
      }
    } else {
#pragma unroll
      for (int i = 0; i < 4; i++) gp[w][1][(q - 2) * 4 + i][nl] = ac1[i];
    }
    __syncthreads();  // #B: partials visible to wave 0
    if (tid < 64) {
      float gh[6];
#pragma unroll
      for (int g2 = 0; g2 < 3; ++g2) {
        float s0 = 0.f, s1 = 0.f;
#pragma unroll
        for (int k2 = 0; k2 < 2; ++k2) {
          int wv = g2 * 2 + k2;
#pragma unroll
          for (int s = 0; s < 3; ++s) {
            s0 += gp[wv][s][m][np];
            s1 += gp[wv][s][m][np + 1];
          }
        }
        gh[g2 * 2] = s0 * ISCL2;
        gh[g2 * 2 + 1] = s1 * ISCL2;
      }
      float r0_ = sigmoidf_(gi6[0] + gh[0] + bh[0]);
      float r1_ = sigmoidf_(gi6[1] + gh[1] + bh[1]);
      float z0_ = sigmoidf_(gi6[2] + gh[2] + bh[2]);
      float z1_ = sigmoidf_(gi6[3] + gh[3] + bh[3]);
      float n0_ = tanhf_(gi6[4] + r0_ * (gh[4] + bh[4]));
      float n1_ = tanhf_(gi6[5] + r1_ * (gh[5] + bh[5]));
      float h0_ = (1.f - z0_) * n0_ + z0_ * hr0;
      float h1_ = (1.f - z1_) * n1_ + z1_ * hr1;
      hr0 = h0_; hr1 = h1_;
      float s0 = h0_ * SCL, s1 = h1_ * SCL;
      _Float16 h0h = (_Float16)s0, h1h = (_Float16)s1;
      _Float16 h0l = (_Float16)(s0 - (float)h0h), h1l = (_Float16)(s1 - (float)h1h);
      u32x4 rec;
      rec[0] = (unsigned)__builtin_bit_cast(unsigned short, h0h) |
               ((unsigned)__builtin_bit_cast(unsigned short, h1h) << 16);
      rec[1] = (unsigned)__builtin_bit_cast(unsigned short, h0l) |
               ((unsigned)__builtin_bit_cast(unsigned short, h1l) << 16);
      rec[2] = (unsigned)(step + 1);
      rec[3] = 0u;
      u32x4* dst = (u32x4*)hrec + ((size_t)((step + 1) & 1) * 4096 + wid * 64 + tid);
      asm volatile("global_store_dwordx4 %0, %1, off sc0 sc1"
                   :: "v"(dst), "v"(rec) : "memory");
      if (step == 511) {
        ctx[m * D + d0] = h0_;
        ctx[m * D + d0 + 1] = h1_;
      }
    }
    // no third barrier: next step's poll is the dataflow barrier
  }
}

// Stage 3: U = ctx @ W_A^T + b_A  (f32 VALU, BW-bound); scaled hi/lo out
__global__ __launch_bounds__(256) void k_u(
    const float* __restrict__ WA, const float* __restrict__ bA,
    const float* __restrict__ ctx, _Float16* __restrict__ Uth,
    _Float16* __restrict__ Utl)
{
  __shared__ float As[128 * 32];
  __shared__ float cx[8][1032];
  int tid = threadIdx.x;
  int RB = blockIdx.x;  // 2048 blocks x 128 rows
#pragma unroll
  for (int jj = 0; jj < 8; ++jj) {
    int e = tid * 32 + jj * 4;
    *(f32x4*)&cx[e >> 10][e & 1023] = *(const f32x4*)(ctx + e);
  }
  float acc[4] = {0.f, 0.f, 0.f, 0.f};
  int b = tid & 7, rq = tid >> 3;
  float* AsW = As + (tid >> 6) * 256;  // wave-uniform staging base (1KB)
  int sr = tid >> 3;
  int sc = (tid & 7) * 4;
  __syncthreads();
  for (int kc = 0; kc < 32; ++kc) {
    __syncthreads();
    const float* gsrc = WA + ((size_t)(RB * 128 + sr)) * D + kc * 32 + sc;
    GLDS16(gsrc, AsW);
    GLDS16(gsrc + 32 * D, AsW + 1024);
    GLDS16(gsrc + 64 * D, AsW + 2048);
    GLDS16(gsrc + 96 * D, AsW + 3072);
    __syncthreads();
    f32x4 cxr[8];
#pragma unroll
    for (int kk = 0; kk < 8; ++kk) cxr[kk] = *(const f32x4*)&cx[b][kc * 32 + kk * 4];
#pragma unroll
    for (int r = 0; r < 4; ++r) {
      const float* ap = As + (rq * 4 + r) * 32;
      float s = 0.f;
#pragma unroll
      for (int kk = 0; kk < 8; ++kk) {
        f32x4 a = *(const f32x4*)(ap + kk * 4);
        f32x4 c = cxr[kk];
        s += a[0] * c[0] + a[1] * c[1] + a[2] * c[2] + a[3] * c[3];
      }
      acc[r] += s;
    }
  }
#pragma unroll
  for (int r = 0; r < 4; ++r) {
    int R = RB * 128 + rq * 4 + r;
    float v = (acc[r] + bA[R]) * SCL;
    int n_u = R >> 8, k_u = R & 255;
    _Float16 hi = (_Float16)v;
    size_t o = ((size_t)(b * 256 + k_u)) * NU + n_u;  // k-major for stage-4 frags
    Uth[o] = hi;
    Utl[o] = (_Float16)(v - (float)hi);
  }
}

// Stage 4: logits[b][v] = sum_k (sum_n eg[v][n] U[b][n][k])^2  (split-f16)
// v2: 128 v-rows/block, 8 waves (wv = v-half, wk = k-slice) -> Ut L3 traffic
// halved; eg loads are plain (L3-cacheable) so the 4x kg re-stage hits L3.
__global__ __launch_bounds__(512, 1) void k_logits(
    const float* __restrict__ eg, const _Float16* __restrict__ Uth,
    const _Float16* __restrict__ Utl, float* __restrict__ out)
{
  __shared__ _Float16 Ash[128 * 40];  // 128 v-rows x 32 n (padded)
  __shared__ _Float16 Asl[128 * 40];
  __shared__ float lacc[8][128];
  int tid = threadIdx.x;
  int v0 = blockIdx.x * 128;
  int lane = tid & 63, w = tid >> 6, nl = lane & 15, q = lane >> 4;
  int wk = w & 3, wv = w >> 2;
  for (int i = tid; i < 1024; i += 512) ((float*)lacc)[i] = 0.f;
  int sr = tid >> 2;
  int sc = (tid & 3) * 8;
  int vr = v0 + sr;
  if (vr >= NV) vr = NV - 1;
  const float* asrc = eg + (size_t)vr * NU;
  f32x4 zero = {0, 0, 0, 0};
  __syncthreads();
  for (int kg = 0; kg < 4; ++kg) {
    f32x4 acc[8][4];
#pragma unroll
    for (int b = 0; b < 8; ++b)
#pragma unroll
      for (int mt = 0; mt < 4; ++mt) acc[b][mt] = zero;
    for (int nc = 0; nc < 32; ++nc) {
      __syncthreads();
      {
        const f32x4* p = (const f32x4*)(asrc + nc * 32 + sc);
        f32x4 u0 = p[0];
        f32x4 u1 = p[1];
        half8 h, l;
#pragma unroll
        for (int j = 0; j < 4; ++j) {
          float s0 = u0[j] * SCL;
          _Float16 h0 = (_Float16)s0;
          h[j] = h0; l[j] = (_Float16)(s0 - (float)h0);
          float s1 = u1[j] * SCL;
          _Float16 h1 = (_Float16)s1;
          h[j + 4] = h1; l[j + 4] = (_Float16)(s1 - (float)h1);
        }
        *(half8*)(Ash + sr * 40 + sc) = h;
        *(half8*)(Asl + sr * 40 + sc) = l;
      }
      __syncthreads();
      half8 afh[4], afl[4];
#pragma unroll
      for (int mt = 0; mt < 4; ++mt) {
        afh[mt] = *(const half8*)(Ash + (wv * 64 + mt * 16 + nl) * 40 + q * 8);
        afl[mt] = *(const half8*)(Asl + (wv * 64 + mt * 16 + nl) * 40 + q * 8);
      }
#pragma unroll
      for (int b = 0; b < 8; ++b) {
        size_t o = ((size_t)(b * 256 + kg * 64 + wk * 16 + nl)) * NU + nc * 32 + q * 8;
        half8 bfh = *(const half8*)(Uth + o);
        half8 bfl = *(const half8*)(Utl + o);
#pragma unroll
        for (int mt = 0; mt < 4; ++mt) {
          acc[b][mt] = __builtin_amdgcn_mfma_f32_16x16x32_f16(afh[mt], bfh, acc[b][mt], 0, 0, 0);
          acc[b][mt] = __builtin_amdgcn_mfma_f32_16x16x32_f16(afh[mt], bfl, acc[b][mt], 0, 0, 0);
          acc[b][mt] = __builtin_amdgcn_mfma_f32_16x16x32_f16(afl[mt], bfh, acc[b][mt], 0, 0, 0);
        }
      }
    }
#pragma unroll
    for (int b = 0; b < 8; ++b) {
#pragma unroll
      for (int mt = 0; mt < 4; ++mt) {
#pragma unroll
        for (int i = 0; i < 4; ++i) {
          float s = acc[b][mt][i] * acc[b][mt][i];
          s += __shfl_xor(s, 1);
          s += __shfl_xor(s, 2);
          s += __shfl_xor(s, 4);
          s += __shfl_xor(s, 8);
          if (nl == 0) atomicAdd(&lacc[b][wv * 64 + mt * 16 + q * 4 + i], s);
        }
      }
    }
  }
  __syncthreads();
  if (tid < 128) {
    int v = v0 + tid;
    if (v < NV) {
#pragma unroll
      for (int b = 0; b < 8; ++b) out[(size_t)b * NV + v] = lacc[b][tid] * ISCL4;
    }
  }
}

extern "C" void kernel_launch(void* const* d_in, const int* in_sizes, int n_in,
                              void* d_out, int out_size, void* d_ws, size_t ws_size,
                              hipStream_t stream)
{
  (void)in_sizes; (void)n_in; (void)out_size; (void)ws_size;
  const int* ids = (const int*)d_in[0];
  const float* emb = (const float*)d_in[1];
  const float* Wih = (const float*)d_in[2];
  const float* Whh = (const float*)d_in[3];
  const float* bih = (const float*)d_in[4];
  const float* bhh = (const float*)d_in[5];
  const float* WA = (const float*)d_in[6];
  const float* bA = (const float*)d_in[7];
  const float* eg = (const float*)d_in[8];
  float* out = (float*)d_out;

  char* ws = (char*)d_ws;
  size_t off = 0;
  auto take = [&](size_t bytes) -> char* {
    char* p = ws + off;
    off += (bytes + 255) & ~(size_t)255;
    return p;
  };
  float* gi32 = (float*)take((size_t)4096 * 3072 * 4);        // 50.3 MB
  char* xregion = take((size_t)4096 * 1024 * 2 * 2);          // x hi+lo 16.8 MB
  _Float16* xh = (_Float16*)xregion;
  _Float16* xl = xh + (size_t)4096 * 1024;
  _Float16* wh = (_Float16*)take((size_t)3072 * 1024 * 2);
  _Float16* wl = (_Float16*)take((size_t)3072 * 1024 * 2);
  unsigned* hrec = (unsigned*)take((size_t)2 * 4096 * 16);    // h record dbuf 128KB
  float* ctx = (float*)take((size_t)8 * 1024 * 4);
  // Ut aliases the x region (x dead after k_gi; Ut written by k_u afterwards)
  _Float16* Uth = (_Float16*)xregion;
  _Float16* Utl = Uth + (size_t)8 * 256 * 1024;

  k_prep<<<dim3(7168), dim3(256), 0, stream>>>(ids, emb, Wih, xh, xl, wh, wl);
  k_gi<<<dim3(32, 24), dim3(256), 0, stream>>>(xh, xl, wh, wl, bih, gi32);
  k_init<<<dim3(1), dim3(256), 0, stream>>>(hrec);
  k_gru<<<dim3(64), dim3(384), 0, stream>>>(Whh, gi32, bhh, hrec, ctx);
  k_u<<<dim3(2048), dim3(256), 0, stream>>>(WA, bA, ctx, Uth, Utl);
  k_logits<<<dim3(393), dim3(512), 0, stream>>>(eg, Uth, Utl, out);
}

// Round 9
// 3058.587 us; speedup vs baseline: 1.3209x; 1.1584x over previous
//
#include <hip/hip_runtime.h>

#define D 1024
#define G3 3072
#define NV 50257
#define NU 1024
#define KU 256
#define TOKROWS 4096
#define SCL 256.0f
#define ISCL2 (1.0f / 65536.0f)
#define ISCL4 (1.0f / 4294967296.0f)

typedef __attribute__((ext_vector_type(8))) _Float16 half8;
typedef __attribute__((ext_vector_type(4))) _Float16 half4;
typedef __attribute__((ext_vector_type(4))) float f32x4;
typedef __attribute__((ext_vector_type(4))) unsigned u32x4;

#define GLDS16(gp, lp) __builtin_amdgcn_global_load_lds( \
    (const __attribute__((address_space(1))) void*)(const void*)(gp), \
    (__attribute__((address_space(3))) void*)(void*)(lp), 16, 0, 0)

static __device__ __forceinline__ float sigmoidf_(float x) {
  return 1.0f / (1.0f + __expf(-x));
}
static __device__ __forceinline__ float tanhf_(float x) {
  float e = __expf(2.0f * x);
  return 1.0f - 2.0f / (e + 1.0f);
}

// Stage 0: gather x and convert W_ih to scaled hi/lo f16 pairs
__global__ __launch_bounds__(256) void k_prep(
    const int* __restrict__ ids, const float* __restrict__ emb,
    const float* __restrict__ Wih,
    _Float16* __restrict__ xh, _Float16* __restrict__ xl,
    _Float16* __restrict__ wh, _Float16* __restrict__ wl)
{
  int t = threadIdx.x;
  int wg = blockIdx.x;
  const float* src;
  _Float16 *dh, *dl;
  if (wg < TOKROWS) {
    src = emb + (size_t)ids[wg] * D;
    dh = xh + (size_t)wg * D; dl = xl + (size_t)wg * D;
  } else {
    int r = wg - TOKROWS;
    src = Wih + (size_t)r * D;
    dh = wh + (size_t)r * D; dl = wl + (size_t)r * D;
  }
  f32x4 v = ((const f32x4*)src)[t];
  half4 h, l;
#pragma unroll
  for (int j = 0; j < 4; ++j) {
    float vs = v[j] * SCL;
    _Float16 hi = (_Float16)vs;
    h[j] = hi;
    l[j] = (_Float16)(vs - (float)hi);
  }
  *(half4*)(dh + t * 4) = h;
  *(half4*)(dl + t * 4) = l;
}

// Stage 1: gi = x @ W_ih^T + b_ih  (split-f16 MFMA, f32 out)
__global__ __launch_bounds__(256) void k_gi(
    const _Float16* __restrict__ Ah, const _Float16* __restrict__ Al,
    const _Float16* __restrict__ Bh, const _Float16* __restrict__ Bl,
    const float* __restrict__ bih, float* __restrict__ gi)
{
  __shared__ _Float16 Ash[128 * 32];
  __shared__ _Float16 Asl[128 * 32];
  __shared__ _Float16 Bsh[128 * 32];
  __shared__ _Float16 Bsl[128 * 32];
  int tid = threadIdx.x;
  int bm = blockIdx.x, bn = blockIdx.y;
  int lane = tid & 63, w = tid >> 6;
  int nl = lane & 15, q = lane >> 4;
  int wr = w >> 1, wc = w & 1;
  f32x4 zero = {0.f, 0.f, 0.f, 0.f};
  f32x4 acc[4][4];
#pragma unroll
  for (int i = 0; i < 4; i++)
#pragma unroll
    for (int j = 0; j < 4; j++) acc[i][j] = zero;
  int r0 = tid >> 2;
  int c0 = (tid & 3) * 8;
  int wb = w * 512;  // wave-uniform LDS staging base (16 rows x 32)
  for (int kc = 0; kc < 32; ++kc) {
    __syncthreads();
    size_t go = ((size_t)(bm * 128 + r0)) * D + kc * 32 + c0;
    size_t go2 = ((size_t)(bn * 128 + r0)) * D + kc * 32 + c0;
    GLDS16(Ah + go, Ash + wb);
    GLDS16(Ah + go + 64 * D, Ash + wb + 2048);
    GLDS16(Al + go, Asl + wb);
    GLDS16(Al + go + 64 * D, Asl + wb + 2048);
    GLDS16(Bh + go2, Bsh + wb);
    GLDS16(Bh + go2 + 64 * D, Bsh + wb + 2048);
    GLDS16(Bl + go2, Bsl + wb);
    GLDS16(Bl + go2 + 64 * D, Bsl + wb + 2048);
    __syncthreads();
    half8 afh[4], afl[4], bfh[4], bfl[4];
#pragma unroll
    for (int mt = 0; mt < 4; ++mt) {
      int o = (wr * 64 + mt * 16 + nl) * 32 + q * 8;
      afh[mt] = *(const half8*)(Ash + o);
      afl[mt] = *(const half8*)(Asl + o);
    }
#pragma unroll
    for (int nt = 0; nt < 4; ++nt) {
      int o = (wc * 64 + nt * 16 + nl) * 32 + q * 8;
      bfh[nt] = *(const half8*)(Bsh + o);
      bfl[nt] = *(const half8*)(Bsl + o);
    }
#pragma unroll
    for (int mt = 0; mt < 4; ++mt)
#pragma unroll
      for (int nt = 0; nt < 4; ++nt) {
        acc[mt][nt] = __builtin_amdgcn_mfma_f32_16x16x32_f16(afh[mt], bfh[nt], acc[mt][nt], 0, 0, 0);
        acc[mt][nt] = __builtin_amdgcn_mfma_f32_16x16x32_f16(afh[mt], bfl[nt], acc[mt][nt], 0, 0, 0);
        acc[mt][nt] = __builtin_amdgcn_mfma_f32_16x16x32_f16(afl[mt], bfh[nt], acc[mt][nt], 0, 0, 0);
      }
  }
#pragma unroll
  for (int mt = 0; mt < 4; ++mt)
#pragma unroll
    for (int nt = 0; nt < 4; ++nt) {
      int col = bn * 128 + wc * 64 + nt * 16 + nl;
      float bv = bih[col];
#pragma unroll
      for (int i = 0; i < 4; i++) {
        int row = bm * 128 + wr * 64 + mt * 16 + q * 4 + i;
        gi[(size_t)row * G3 + col] = acc[mt][nt][i] * ISCL2 + bv;
      }
    }
}

// init: zero the h-record double buffer (2 x 4096 records x 16B); tags become 0,
// which is exactly what step 0 polls for (h(0)=0). Must run every launch (replay).
__global__ void k_init(unsigned* __restrict__ rec32)
{
  int t = threadIdx.x;
  for (int i = t; i < 32768; i += 256) rec32[i] = 0u;
}

// Stage 2 (R6-proven, frozen): GRU scan, 64 WGs x 6 waves. h exchanged as 16B
// records {pkh, pkl, tag, pad}; tag rides with the data (dataflow barrier,
// exact-tag match is skew-safe); bulk load + per-chunk tag-verify IS the poll.
__global__ __launch_bounds__(384) void k_gru(
    const float* __restrict__ Whh, const float* __restrict__ gi,
    const float* __restrict__ bhh, unsigned* __restrict__ hrec,
    float* __restrict__ ctx)
{
  int tid = threadIdx.x;
  int wid = blockIdx.x;           // 64 WGs, d-slice of 16 each
  int w = tid >> 6;               // 6 waves
  int g = w >> 1;                 // gate: 0=r 1=z 2=n
  int kh = w & 1;                 // K half (512 each)
  int lane = tid & 63, nl = lane & 15, q = lane >> 4;
  __shared__ _Float16 hs[16 * 1024];   // unpacked h (32 KB), 16B-chunk XOR swizzle
  __shared__ float gp[6][3][8][17];    // [wave][slot][batch][d] partials

  // W_hh slice -> registers, scaled hi/lo f16 B-fragments
  half8 bwh[16], bwl[16];
  {
    const float* wrow = Whh + ((size_t)(g * 1024 + wid * 16 + nl)) * D + kh * 512;
#pragma unroll
    for (int kt = 0; kt < 16; ++kt) {
      const f32x4* p = (const f32x4*)(wrow + kt * 32 + q * 8);
      f32x4 v0 = p[0], v1 = p[1];
      half8 h, l;
#pragma unroll
      for (int j = 0; j < 4; ++j) {
        float s0 = v0[j] * SCL;
        _Float16 h0 = (_Float16)s0;
        h[j] = h0; l[j] = (_Float16)(s0 - (float)h0);
        float s1 = v1[j] * SCL;
        _Float16 h1 = (_Float16)s1;
        h[j + 4] = h1; l[j + 4] = (_Float16)(s1 - (float)h1);
      }
      bwh[kt] = h; bwl[kt] = l;
    }
  }

  // update-role state (wave 0): each thread owns (batch m, dims d0,d0+1)
  int m = tid >> 3, np = (tid & 7) * 2;
  int d0 = wid * 16 + np;
  float hr0 = 0.f, hr1 = 0.f;
  float bh[6] = {0, 0, 0, 0, 0, 0};
  if (tid < 64) {
#pragma unroll
    for (int gg = 0; gg < 3; ++gg) {
      bh[gg * 2] = bhh[gg * 1024 + d0];
      bh[gg * 2 + 1] = bhh[gg * 1024 + d0 + 1];
    }
  }
  f32x4 zero = {0, 0, 0, 0};

  for (int step = 0; step < 512; ++step) {
    float gi6[6] = {0, 0, 0, 0, 0, 0};
    if (tid < 64) {  // gi for this step (f32, plain cached loads; drain in poll)
      const float* gpt = gi + ((size_t)(m * 512 + step)) * G3 + d0;
#pragma unroll
      for (int gg = 0; gg < 3; ++gg) {
        gi6[gg * 2] = gpt[gg * 1024];
        gi6[gg * 2 + 1] = gpt[gg * 1024 + 1];
      }
    }

    // ---- poll h records (tag == step) and unpack into LDS ----
    {
      unsigned want = (unsigned)step;
      const u32x4* rb = (const u32x4*)hrec + (size_t)(step & 1) * 4096;
      u32x4 rv[11];
      unsigned need = 0;
#pragma unroll
      for (int k = 0; k < 11; ++k) {
        int r = tid + k * 384;
        if (r < 4096) need |= (1u << k);
      }
      while (need) {
        unsigned mm = need;
#pragma unroll
        for (int k = 0; k < 11; ++k)
          if (mm & (1u << k)) {
            int r = tid + k * 384;
            asm volatile("global_load_dwordx4 %0, %1, off sc0 sc1"
                         : "=v"(rv[k]) : "v"(rb + r));
          }
        asm volatile("s_waitcnt vmcnt(0)" ::: "memory");
#pragma unroll
        for (int k = 0; k < 11; ++k)
          if ((mm & (1u << k)) && rv[k][2] == want) need &= ~(1u << k);
      }
      __builtin_amdgcn_sched_barrier(0);
#pragma unroll
      for (int k = 0; k < 11; ++k) {
        int r = tid + k * 384;
        if (r < 4096) {
          int w2 = r >> 6, l2 = r & 63;
          int m2 = l2 >> 3;
          int d = (w2 << 4) + ((l2 & 7) << 1);
          int chunk = d >> 3, wi = d & 7;
          int sw = chunk ^ (m2 & 7);
          *(unsigned*)&hs[((m2 * 128 + sw) << 3) + wi] = rv[k][0];          // hi row
          *(unsigned*)&hs[(((m2 + 8) * 128 + sw) << 3) + wi] = rv[k][1];    // lo row
        }
      }
    }
    __syncthreads();  // #A: staged h visible

    // A fragments from LDS (swizzled chunks), then MFMA
    half8 av[16];
#pragma unroll
    for (int kt = 0; kt < 16; ++kt) {
      int chunk = kh * 64 + kt * 4 + q;
      av[kt] = *(const half8*)&hs[(size_t)(nl * 128 + (chunk ^ (nl & 7))) * 8];
    }
    f32x4 ac1 = zero, ac2 = zero;
#pragma unroll
    for (int kt = 0; kt < 16; ++kt) {
      ac1 = __builtin_amdgcn_mfma_f32_16x16x32_f16(av[kt], bwh[kt], ac1, 0, 0, 0);
      ac2 = __builtin_amdgcn_mfma_f32_16x16x32_f16(av[kt], bwl[kt], ac2, 0, 0, 0);
    }
    // partials: slot0 = hi@Wh (rows 0-7), slot1 = lo@Wh (rows 8-15), slot2 = hi@Wl
    if (q < 2) {
#pragma unroll
      for (int i = 0; i < 4; i++) {
        gp[w][0][q * 4 + i][nl] = ac1[i];
        gp[w][2][q * 4 + i][nl] = ac2[i];
      }
    } else {
#pragma unroll
      for (int i = 0; i < 4; i++) gp[w][1][(q - 2) * 4 + i][nl] = ac1[i];
    }
    __syncthreads();  // #B: partials visible to wave 0
    if (tid < 64) {
      float gh[6];
#pragma unroll
      for (int g2 = 0; g2 < 3; ++g2) {
        float s0 = 0.f, s1 = 0.f;
#pragma unroll
        for (int k2 = 0; k2 < 2; ++k2) {
          int wv = g2 * 2 + k2;
#pragma unroll
          for (int s = 0; s < 3; ++s) {
            s0 += gp[wv][s][m][np];
            s1 += gp[wv][s][m][np + 1];
          }
        }
        gh[g2 * 2] = s0 * ISCL2;
        gh[g2 * 2 + 1] = s1 * ISCL2;
      }
      float r0_ = sigmoidf_(gi6[0] + gh[0] + bh[0]);
      float r1_ = sigmoidf_(gi6[1] + gh[1] + bh[1]);
      float z0_ = sigmoidf_(gi6[2] + gh[2] + bh[2]);
      float z1_ = sigmoidf_(gi6[3] + gh[3] + bh[3]);
      float n0_ = tanhf_(gi6[4] + r0_ * (gh[4] + bh[4]));
      float n1_ = tanhf_(gi6[5] + r1_ * (gh[5] + bh[5]));
      float h0_ = (1.f - z0_) * n0_ + z0_ * hr0;
      float h1_ = (1.f - z1_) * n1_ + z1_ * hr1;
      hr0 = h0_; hr1 = h1_;
      float s0 = h0_ * SCL, s1 = h1_ * SCL;
      _Float16 h0h = (_Float16)s0, h1h = (_Float16)s1;
      _Float16 h0l = (_Float16)(s0 - (float)h0h), h1l = (_Float16)(s1 - (float)h1h);
      u32x4 rec;
      rec[0] = (unsigned)__builtin_bit_cast(unsigned short, h0h) |
               ((unsigned)__builtin_bit_cast(unsigned short, h1h) << 16);
      rec[1] = (unsigned)__builtin_bit_cast(unsigned short, h0l) |
               ((unsigned)__builtin_bit_cast(unsigned short, h1l) << 16);
      rec[2] = (unsigned)(step + 1);
      rec[3] = 0u;
      u32x4* dst = (u32x4*)hrec + ((size_t)((step + 1) & 1) * 4096 + wid * 64 + tid);
      asm volatile("global_store_dwordx4 %0, %1, off sc0 sc1"
                   :: "v"(dst), "v"(rec) : "memory");
      if (step == 511) {
        ctx[m * D + d0] = h0_;
        ctx[m * D + d0 + 1] = h1_;
      }
    }
    // no third barrier: next step's poll is the dataflow barrier
  }
}

// Stage 3: U = ctx @ W_A^T + b_A  (f32 VALU, BW-bound); scaled hi/lo out
__global__ __launch_bounds__(256) void k_u(
    const float* __restrict__ WA, const float* __restrict__ bA,
    const float* __restrict__ ctx, _Float16* __restrict__ Uth,
    _Float16* __restrict__ Utl)
{
  __shared__ float As[128 * 32];
  __shared__ float cx[8][1032];
  int tid = threadIdx.x;
  int RB = blockIdx.x;  // 2048 blocks x 128 rows
#pragma unroll
  for (int jj = 0; jj < 8; ++jj) {
    int e = tid * 32 + jj * 4;
    *(f32x4*)&cx[e >> 10][e & 1023] = *(const f32x4*)(ctx + e);
  }
  float acc[4] = {0.f, 0.f, 0.f, 0.f};
  int b = tid & 7, rq = tid >> 3;
  float* AsW = As + (tid >> 6) * 256;  // wave-uniform staging base (1KB)
  int sr = tid >> 3;
  int sc = (tid & 7) * 4;
  __syncthreads();
  for (int kc = 0; kc < 32; ++kc) {
    __syncthreads();
    const float* gsrc = WA + ((size_t)(RB * 128 + sr)) * D + kc * 32 + sc;
    GLDS16(gsrc, AsW);
    GLDS16(gsrc + 32 * D, AsW + 1024);
    GLDS16(gsrc + 64 * D, AsW + 2048);
    GLDS16(gsrc + 96 * D, AsW + 3072);
    __syncthreads();
    f32x4 cxr[8];
#pragma unroll
    for (int kk = 0; kk < 8; ++kk) cxr[kk] = *(const f32x4*)&cx[b][kc * 32 + kk * 4];
#pragma unroll
    for (int r = 0; r < 4; ++r) {
      const float* ap = As + (rq * 4 + r) * 32;
      float s = 0.f;
#pragma unroll
      for (int kk = 0; kk < 8; ++kk) {
        f32x4 a = *(const f32x4*)(ap + kk * 4);
        f32x4 c = cxr[kk];
        s += a[0] * c[0] + a[1] * c[1] + a[2] * c[2] + a[3] * c[3];
      }
      acc[r] += s;
    }
  }
#pragma unroll
  for (int r = 0; r < 4; ++r) {
    int R = RB * 128 + rq * 4 + r;
    float v = (acc[r] + bA[R]) * SCL;
    int n_u = R >> 8, k_u = R & 255;
    _Float16 hi = (_Float16)v;
    size_t o = ((size_t)(b * 256 + k_u)) * NU + n_u;  // k-major for stage-4 frags
    Uth[o] = hi;
    Utl[o] = (_Float16)(v - (float)hi);
  }
}

// Stage 4 v3: logits[b][v] = sum_k (sum_n eg[v][n] U[b][n][k])^2  (split-f16)
// 8 waves = (bh: 4-batch half) x (wk: 4 k-slices); mt=8 -> 128 v-rows PER WAVE.
// Halves Ut L3 traffic (3.3 GB) and halves per-wave B-load instructions vs v1/v2.
__global__ __launch_bounds__(512, 1) void k_logits(
    const float* __restrict__ eg, const _Float16* __restrict__ Uth,
    const _Float16* __restrict__ Utl, float* __restrict__ out)
{
  __shared__ _Float16 Ash[128 * 40];  // 128 v-rows x 32 n (padded)
  __shared__ _Float16 Asl[128 * 40];
  __shared__ float lacc[8][128];
  int tid = threadIdx.x;
  int v0 = blockIdx.x * 128;
  int lane = tid & 63, w = tid >> 6, nl = lane & 15, q = lane >> 4;
  int bh = w & 1, wk = w >> 1;   // batch half, k-slice
  for (int i = tid; i < 1024; i += 512) ((float*)lacc)[i] = 0.f;
  int sr = tid >> 2;          // 0..127 staged v-row
  int sc = (tid & 3) * 8;     // n offset
  int vr = v0 + sr;
  if (vr >= NV) vr = NV - 1;
  const float* asrc = eg + (size_t)vr * NU;
  f32x4 zero = {0, 0, 0, 0};
  __syncthreads();
  for (int kg = 0; kg < 4; ++kg) {
    f32x4 acc[4][8];  // [b'][mt]
#pragma unroll
    for (int b = 0; b < 4; ++b)
#pragma unroll
      for (int mt = 0; mt < 8; ++mt) acc[b][mt] = zero;
    for (int nc = 0; nc < 32; ++nc) {
      __syncthreads();
      {
        const f32x4* p = (const f32x4*)(asrc + nc * 32 + sc);
        f32x4 u0 = p[0];
        f32x4 u1 = p[1];
        half8 h, l;
#pragma unroll
        for (int j = 0; j < 4; ++j) {
          float s0 = u0[j] * SCL;
          _Float16 h0 = (_Float16)s0;
          h[j] = h0; l[j] = (_Float16)(s0 - (float)h0);
          float s1 = u1[j] * SCL;
          _Float16 h1 = (_Float16)s1;
          h[j + 4] = h1; l[j + 4] = (_Float16)(s1 - (float)h1);
        }
        *(half8*)(Ash + sr * 40 + sc) = h;
        *(half8*)(Asl + sr * 40 + sc) = l;
      }
      __syncthreads();
      half8 afh[8], afl[8];
#pragma unroll
      for (int mt = 0; mt < 8; ++mt) {
        afh[mt] = *(const half8*)(Ash + (mt * 16 + nl) * 40 + q * 8);
        afl[mt] = *(const half8*)(Asl + (mt * 16 + nl) * 40 + q * 8);
      }
#pragma unroll
      for (int b = 0; b < 4; ++b) {
        int bb = bh * 4 + b;
        size_t o = ((size_t)(bb * 256 + kg * 64 + wk * 16 + nl)) * NU + nc * 32 + q * 8;
        half8 bfh = *(const half8*)(Uth + o);
        half8 bfl = *(const half8*)(Utl + o);
#pragma unroll
        for (int mt = 0; mt < 8; ++mt) {
          acc[b][mt] = __builtin_amdgcn_mfma_f32_16x16x32_f16(afh[mt], bfh, acc[b][mt], 0, 0, 0);
          acc[b][mt] = __builtin_amdgcn_mfma_f32_16x16x32_f16(afh[mt], bfl, acc[b][mt], 0, 0, 0);
          acc[b][mt] = __builtin_amdgcn_mfma_f32_16x16x32_f16(afl[mt], bfh, acc[b][mt], 0, 0, 0);
        }
      }
    }
#pragma unroll
    for (int b = 0; b < 4; ++b) {
      int bb = bh * 4 + b;
#pragma unroll
      for (int mt = 0; mt < 8; ++mt) {
#pragma unroll
        for (int i = 0; i < 4; ++i) {
          float s = acc[b][mt][i] * acc[b][mt][i];
          s += __shfl_xor(s, 1);
          s += __shfl_xor(s, 2);
          s += __shfl_xor(s, 4);
          s += __shfl_xor(s, 8);
          if (nl == 0) atomicAdd(&lacc[bb][mt * 16 + q * 4 + i], s);
        }
      }
    }
  }
  __syncthreads();
  if (tid < 128) {
    int v = v0 + tid;
    if (v < NV) {
#pragma unroll
      for (int b = 0; b < 8; ++b) out[(size_t)b * NV + v] = lacc[b][tid] * ISCL4;
    }
  }
}

extern "C" void kernel_launch(void* const* d_in, const int* in_sizes, int n_in,
                              void* d_out, int out_size, void* d_ws, size_t ws_size,
                              hipStream_t stream)
{
  (void)in_sizes; (void)n_in; (void)out_size; (void)ws_size;
  const int* ids = (const int*)d_in[0];
  const float* emb = (const float*)d_in[1];
  const float* Wih = (const float*)d_in[2];
  const float* Whh = (const float*)d_in[3];
  const float* bih = (const float*)d_in[4];
  const float* bhh = (const float*)d_in[5];
  const float* WA = (const float*)d_in[6];
  const float* bA = (const float*)d_in[7];
  const float* eg = (const float*)d_in[8];
  float* out = (float*)d_out;

  char* ws = (char*)d_ws;
  size_t off = 0;
  auto take = [&](size_t bytes) -> char* {
    char* p = ws + off;
    off += (bytes + 255) & ~(size_t)255;
    return p;
  };
  float* gi32 = (float*)take((size_t)4096 * 3072 * 4);        // 50.3 MB
  char* xregion = take((size_t)4096 * 1024 * 2 * 2);          // x hi+lo 16.8 MB
  _Float16* xh = (_Float16*)xregion;
  _Float16* xl = xh + (size_t)4096 * 1024;
  _Float16* wh = (_Float16*)take((size_t)3072 * 1024 * 2);
  _Float16* wl = (_Float16*)take((size_t)3072 * 1024 * 2);
  unsigned* hrec = (unsigned*)take((size_t)2 * 4096 * 16);    // h record dbuf 128KB
  float* ctx = (float*)take((size_t)8 * 1024 * 4);
  // Ut aliases the x region (x dead after k_gi; Ut written by k_u afterwards)
  _Float16* Uth = (_Float16*)xregion;
  _Float16* Utl = Uth + (size_t)8 * 256 * 1024;

  k_prep<<<dim3(7168), dim3(256), 0, stream>>>(ids, emb, Wih, xh, xl, wh, wl);
  k_gi<<<dim3(32, 24), dim3(256), 0, stream>>>(xh, xl, wh, wl, bih, gi32);
  k_init<<<dim3(1), dim3(256), 0, stream>>>(hrec);
  k_gru<<<dim3(64), dim3(384), 0, stream>>>(Whh, gi32, bhh, hrec, ctx);
  k_u<<<dim3(2048), dim3(256), 0, stream>>>(WA, bA, ctx, Uth, Utl);
  k_logits<<<dim3(393), dim3(512), 0, stream>>>(eg, Uth, Utl, out);
}

// Round 10
// 3037.116 us; speedup vs baseline: 1.3303x; 1.0071x over previous
//
#include <hip/hip_runtime.h>

#define D 1024
#define G3 3072
#define NV 50257
#define NU 1024
#define KU 256
#define TOKROWS 4096
#define SCL 256.0f
#define ISCL2 (1.0f / 65536.0f)
#define ISCL4 (1.0f / 4294967296.0f)

typedef __attribute__((ext_vector_type(8))) _Float16 half8;
typedef __attribute__((ext_vector_type(4))) _Float16 half4;
typedef __attribute__((ext_vector_type(4))) float f32x4;
typedef __attribute__((ext_vector_type(4))) unsigned u32x4;

#define GLDS16(gp, lp) __builtin_amdgcn_global_load_lds( \
    (const __attribute__((address_space(1))) void*)(const void*)(gp), \
    (__attribute__((address_space(3))) void*)(void*)(lp), 16, 0, 0)

static __device__ __forceinline__ float sigmoidf_(float x) {
  return 1.0f / (1.0f + __expf(-x));
}
static __device__ __forceinline__ float tanhf_(float x) {
  float e = __expf(2.0f * x);
  return 1.0f - 2.0f / (e + 1.0f);
}

// Stage 0: gather x and convert W_ih to scaled hi/lo f16 pairs
__global__ __launch_bounds__(256) void k_prep(
    const int* __restrict__ ids, const float* __restrict__ emb,
    const float* __restrict__ Wih,
    _Float16* __restrict__ xh, _Float16* __restrict__ xl,
    _Float16* __restrict__ wh, _Float16* __restrict__ wl)
{
  int t = threadIdx.x;
  int wg = blockIdx.x;
  const float* src;
  _Float16 *dh, *dl;
  if (wg < TOKROWS) {
    src = emb + (size_t)ids[wg] * D;
    dh = xh + (size_t)wg * D; dl = xl + (size_t)wg * D;
  } else {
    int r = wg - TOKROWS;
    src = Wih + (size_t)r * D;
    dh = wh + (size_t)r * D; dl = wl + (size_t)r * D;
  }
  f32x4 v = ((const f32x4*)src)[t];
  half4 h, l;
#pragma unroll
  for (int j = 0; j < 4; ++j) {
    float vs = v[j] * SCL;
    _Float16 hi = (_Float16)vs;
    h[j] = hi;
    l[j] = (_Float16)(vs - (float)hi);
  }
  *(half4*)(dh + t * 4) = h;
  *(half4*)(dl + t * 4) = l;
}

// Stage 1 v2: gi = x @ W_ih^T + b_ih  (split-f16 MFMA, f32 out)
// K-step 64 (16 barrier-pairs, 96 MFMA/wave/step). LDS linear dest for
// global_load_lds + pre-swizzled GLOBAL source (chunk ^= row&7) + XOR on the
// frag read: bank-conflict-free ds_read_b128 at row stride 128B.
__global__ __launch_bounds__(256) void k_gi(
    const _Float16* __restrict__ Ah, const _Float16* __restrict__ Al,
    const _Float16* __restrict__ Bh, const _Float16* __restrict__ Bl,
    const float* __restrict__ bih, float* __restrict__ gi)
{
  __shared__ _Float16 Ash[128 * 64];
  __shared__ _Float16 Asl[128 * 64];
  __shared__ _Float16 Bsh[128 * 64];
  __shared__ _Float16 Bsl[128 * 64];
  int tid = threadIdx.x;
  int bm = blockIdx.x, bn = blockIdx.y;
  int lane = tid & 63, w = tid >> 6;
  int nl = lane & 15, q = lane >> 4;
  int wr = w >> 1, wc = w & 1;
  f32x4 zero = {0.f, 0.f, 0.f, 0.f};
  f32x4 acc[4][4];
#pragma unroll
  for (int i = 0; i < 4; i++)
#pragma unroll
    for (int j = 0; j < 4; j++) acc[i][j] = zero;
  // staging: sweep s covers rows s*32 + (tid>>3); within-row chunk = tid&7.
  // global col chunk is pre-swizzled so LDS (linear) ends up swizzled:
  int srow_in = tid >> 3;                       // 0..31
  int cg = ((tid & 7) ^ (srow_in & 7)) * 8;     // swizzled global col (f16)
  for (int kc = 0; kc < 16; ++kc) {
    __syncthreads();
#pragma unroll
    for (int s = 0; s < 4; ++s) {
      size_t go = ((size_t)(bm * 128 + s * 32 + srow_in)) * D + kc * 64 + cg;
      size_t go2 = ((size_t)(bn * 128 + s * 32 + srow_in)) * D + kc * 64 + cg;
      int lb = s * 2048 + w * 512;              // wave-uniform LDS base (f16)
      GLDS16(Ah + go, Ash + lb);
      GLDS16(Al + go, Asl + lb);
      GLDS16(Bh + go2, Bsh + lb);
      GLDS16(Bl + go2, Bsl + lb);
    }
    __syncthreads();
    half8 afh[4][2], afl[4][2], bfh[4][2], bfl[4][2];
#pragma unroll
    for (int mt = 0; mt < 4; ++mt) {
      int R = wr * 64 + mt * 16 + nl;
#pragma unroll
      for (int kt = 0; kt < 2; ++kt) {
        int o = R * 64 + ((kt * 4 + q) ^ (R & 7)) * 8;
        afh[mt][kt] = *(const half8*)(Ash + o);
        afl[mt][kt] = *(const half8*)(Asl + o);
      }
    }
#pragma unroll
    for (int nt = 0; nt < 4; ++nt) {
      int R = wc * 64 + nt * 16 + nl;
#pragma unroll
      for (int kt = 0; kt < 2; ++kt) {
        int o = R * 64 + ((kt * 4 + q) ^ (R & 7)) * 8;
        bfh[nt][kt] = *(const half8*)(Bsh + o);
        bfl[nt][kt] = *(const half8*)(Bsl + o);
      }
    }
#pragma unroll
    for (int mt = 0; mt < 4; ++mt)
#pragma unroll
      for (int nt = 0; nt < 4; ++nt)
#pragma unroll
        for (int kt = 0; kt < 2; ++kt) {
          acc[mt][nt] = __builtin_amdgcn_mfma_f32_16x16x32_f16(afh[mt][kt], bfh[nt][kt], acc[mt][nt], 0, 0, 0);
          acc[mt][nt] = __builtin_amdgcn_mfma_f32_16x16x32_f16(afh[mt][kt], bfl[nt][kt], acc[mt][nt], 0, 0, 0);
          acc[mt][nt] = __builtin_amdgcn_mfma_f32_16x16x32_f16(afl[mt][kt], bfh[nt][kt], acc[mt][nt], 0, 0, 0);
        }
  }
#pragma unroll
  for (int mt = 0; mt < 4; ++mt)
#pragma unroll
    for (int nt = 0; nt < 4; ++nt) {
      int col = bn * 128 + wc * 64 + nt * 16 + nl;
      float bv = bih[col];
#pragma unroll
      for (int i = 0; i < 4; i++) {
        int row = bm * 128 + wr * 64 + mt * 16 + q * 4 + i;
        gi[(size_t)row * G3 + col] = acc[mt][nt][i] * ISCL2 + bv;
      }
    }
}

// init: zero the h-record double buffer (2 x 4096 records x 16B); tags become 0,
// which is exactly what step 0 polls for (h(0)=0). Must run every launch (replay).
__global__ void k_init(unsigned* __restrict__ rec32)
{
  int t = threadIdx.x;
  for (int i = t; i < 32768; i += 256) rec32[i] = 0u;
}

// Stage 2 (R6-proven, frozen): GRU scan, 64 WGs x 6 waves. h exchanged as 16B
// records {pkh, pkl, tag, pad}; tag rides with the data (dataflow barrier,
// exact-tag match is skew-safe); bulk load + per-chunk tag-verify IS the poll.
__global__ __launch_bounds__(384) void k_gru(
    const float* __restrict__ Whh, const float* __restrict__ gi,
    const float* __restrict__ bhh, unsigned* __restrict__ hrec,
    float* __restrict__ ctx)
{
  int tid = threadIdx.x;
  int wid = blockIdx.x;           // 64 WGs, d-slice of 16 each
  int w = tid >> 6;               // 6 waves
  int g = w >> 1;                 // gate: 0=r 1=z 2=n
  int kh = w & 1;                 // K half (512 each)
  int lane = tid & 63, nl = lane & 15, q = lane >> 4;
  __shared__ _Float16 hs[16 * 1024];   // unpacked h (32 KB), 16B-chunk XOR swizzle
  __shared__ float gp[6][3][8][17];    // [wave][slot][batch][d] partials

  // W_hh slice -> registers, scaled hi/lo f16 B-fragments
  half8 bwh[16], bwl[16];
  {
    const float* wrow = Whh + ((size_t)(g * 1024 + wid * 16 + nl)) * D + kh * 512;
#pragma unroll
    for (int kt = 0; kt < 16; ++kt) {
      const f32x4* p = (const f32x4*)(wrow + kt * 32 + q * 8);
      f32x4 v0 = p[0], v1 = p[1];
      half8 h, l;
#pragma unroll
      for (int j = 0; j < 4; ++j) {
        float s0 = v0[j] * SCL;
        _Float16 h0 = (_Float16)s0;
        h[j] = h0; l[j] = (_Float16)(s0 - (float)h0);
        float s1 = v1[j] * SCL;
        _Float16 h1 = (_Float16)s1;
        h[j + 4] = h1; l[j + 4] = (_Float16)(s1 - (float)h1);
      }
      bwh[kt] = h; bwl[kt] = l;
    }
  }

  // update-role state (wave 0): each thread owns (batch m, dims d0,d0+1)
  int m = tid >> 3, np = (tid & 7) * 2;
  int d0 = wid * 16 + np;
  float hr0 = 0.f, hr1 = 0.f;
  float bh[6] = {0, 0, 0, 0, 0, 0};
  if (tid < 64) {
#pragma unroll
    for (int gg = 0; gg < 3; ++gg) {
      bh[gg * 2] = bhh[gg * 1024 + d0];
      bh[gg * 2 + 1] = bhh[gg * 1024 + d0 + 1];
    }
  }
  f32x4 zero = {0, 0, 0, 0};

  for (int step = 0; step < 512; ++step) {
    float gi6[6] = {0, 0, 0, 0, 0, 0};
    if (tid < 64) {  // gi for this step (f32, plain cached loads; drain in poll)
      const float* gpt = gi + ((size_t)(m * 512 + step)) * G3 + d0;
#pragma unroll
      for (int gg = 0; gg < 3; ++gg) {
        gi6[gg * 2] = gpt[gg * 1024];
        gi6[gg * 2 + 1] = gpt[gg * 1024 + 1];
      }
    }

    // ---- poll h records (tag == step) and unpack into LDS ----
    {
      unsigned want = (unsigned)step;
      const u32x4* rb = (const u32x4*)hrec + (size_t)(step & 1) * 4096;
      u32x4 rv[11];
      unsigned need = 0;
#pragma unroll
      for (int k = 0; k < 11; ++k) {
        int r = tid + k * 384;
        if (r < 4096) need |= (1u << k);
      }
      while (need) {
        unsigned mm = need;
#pragma unroll
        for (int k = 0; k < 11; ++k)
          if (mm & (1u << k)) {
            int r = tid + k * 384;
            asm volatile("global_load_dwordx4 %0, %1, off sc0 sc1"
                         : "=v"(rv[k]) : "v"(rb + r));
          }
        asm volatile("s_waitcnt vmcnt(0)" ::: "memory");
#pragma unroll
        for (int k = 0; k < 11; ++k)
          if ((mm & (1u << k)) && rv[k][2] == want) need &= ~(1u << k);
      }
      __builtin_amdgcn_sched_barrier(0);
#pragma unroll
      for (int k = 0; k < 11; ++k) {
        int r = tid + k * 384;
        if (r < 4096) {
          int w2 = r >> 6, l2 = r & 63;
          int m2 = l2 >> 3;
          int d = (w2 << 4) + ((l2 & 7) << 1);
          int chunk = d >> 3, wi = d & 7;
          int sw = chunk ^ (m2 & 7);
          *(unsigned*)&hs[((m2 * 128 + sw) << 3) + wi] = rv[k][0];          // hi row
          *(unsigned*)&hs[(((m2 + 8) * 128 + sw) << 3) + wi] = rv[k][1];    // lo row
        }
      }
    }
    __syncthreads();  // #A: staged h visible

    // A fragments from LDS (swizzled chunks), then MFMA
    half8 av[16];
#pragma unroll
    for (int kt = 0; kt < 16; ++kt) {
      int chunk = kh * 64 + kt * 4 + q;
      av[kt] = *(const half8*)&hs[(size_t)(nl * 128 + (chunk ^ (nl & 7))) * 8];
    }
    f32x4 ac1 = zero, ac2 = zero;
#pragma unroll
    for (int kt = 0; kt < 16; ++kt) {
      ac1 = __builtin_amdgcn_mfma_f32_16x16x32_f16(av[kt], bwh[kt], ac1, 0, 0, 0);
      ac2 = __builtin_amdgcn_mfma_f32_16x16x32_f16(av[kt], bwl[kt], ac2, 0, 0, 0);
    }
    // partials: slot0 = hi@Wh (rows 0-7), slot1 = lo@Wh (rows 8-15), slot2 = hi@Wl
    if (q < 2) {
#pragma unroll
      for (int i = 0; i < 4; i++) {
        gp[w][0][q * 4 + i][nl] = ac1[i];
        gp[w][2][q * 4 + i][nl] = ac2[i];
      }
    } else {
#pragma unroll
      for (int i = 0; i < 4; i++) gp[w][1][(q - 2) * 4 + i][nl] = ac1[i];
    }
    __syncthreads();  // #B: partials visible to wave 0
    if (tid < 64) {
      float gh[6];
#pragma unroll
      for (int g2 = 0; g2 < 3; ++g2) {
        float s0 = 0.f, s1 = 0.f;
#pragma unroll
        for (int k2 = 0; k2 < 2; ++k2) {
          int wv = g2 * 2 + k2;
#pragma unroll
          for (int s = 0; s < 3; ++s) {
            s0 += gp[wv][s][m][np];
            s1 += gp[wv][s][m][np + 1];
          }
        }
        gh[g2 * 2] = s0 * ISCL2;
        gh[g2 * 2 + 1] = s1 * ISCL2;
      }
      float r0_ = sigmoidf_(gi6[0] + gh[0] + bh[0]);
      float r1_ = sigmoidf_(gi6[1] + gh[1] + bh[1]);
      float z0_ = sigmoidf_(gi6[2] + gh[2] + bh[2]);
      float z1_ = sigmoidf_(gi6[3] + gh[3] + bh[3]);
      float n0_ = tanhf_(gi6[4] + r0_ * (gh[4] + bh[4]));
      float n1_ = tanhf_(gi6[5] + r1_ * (gh[5] + bh[5]));
      float h0_ = (1.f - z0_) * n0_ + z0_ * hr0;
      float h1_ = (1.f - z1_) * n1_ + z1_ * hr1;
      hr0 = h0_; hr1 = h1_;
      float s0 = h0_ * SCL, s1 = h1_ * SCL;
      _Float16 h0h = (_Float16)s0, h1h = (_Float16)s1;
      _Float16 h0l = (_Float16)(s0 - (float)h0h), h1l = (_Float16)(s1 - (float)h1h);
      u32x4 rec;
      rec[0] = (unsigned)__builtin_bit_cast(unsigned short, h0h) |
               ((unsigned)__builtin_bit_cast(unsigned short, h1h) << 16);
      rec[1] = (unsigned)__builtin_bit_cast(unsigned short, h0l) |
               ((unsigned)__builtin_bit_cast(unsigned short, h1l) << 16);
      rec[2] = (unsigned)(step + 1);
      rec[3] = 0u;
      u32x4* dst = (u32x4*)hrec + ((size_t)((step + 1) & 1) * 4096 + wid * 64 + tid);
      asm volatile("global_store_dwordx4 %0, %1, off sc0 sc1"
                   :: "v"(dst), "v"(rec) : "memory");
      if (step == 511) {
        ctx[m * D + d0] = h0_;
        ctx[m * D + d0 + 1] = h1_;
      }
    }
    // no third barrier: next step's poll is the dataflow barrier
  }
}

// Stage 3: U = ctx @ W_A^T + b_A  (f32 VALU, BW-bound); scaled hi/lo out
__global__ __launch_bounds__(256) void k_u(
    const float* __restrict__ WA, const float* __restrict__ bA,
    const float* __restrict__ ctx, _Float16* __restrict__ Uth,
    _Float16* __restrict__ Utl)
{
  __shared__ float As[128 * 32];
  __shared__ float cx[8][1032];
  int tid = threadIdx.x;
  int RB = blockIdx.x;  // 2048 blocks x 128 rows
#pragma unroll
  for (int jj = 0; jj < 8; ++jj) {
    int e = tid * 32 + jj * 4;
    *(f32x4*)&cx[e >> 10][e & 1023] = *(const f32x4*)(ctx + e);
  }
  float acc[4] = {0.f, 0.f, 0.f, 0.f};
  int b = tid & 7, rq = tid >> 3;
  float* AsW = As + (tid >> 6) * 256;  // wave-uniform staging base (1KB)
  int sr = tid >> 3;
  int sc = (tid & 7) * 4;
  __syncthreads();
  for (int kc = 0; kc < 32; ++kc) {
    __syncthreads();
    const float* gsrc = WA + ((size_t)(RB * 128 + sr)) * D + kc * 32 + sc;
    GLDS16(gsrc, AsW);
    GLDS16(gsrc + 32 * D, AsW + 1024);
    GLDS16(gsrc + 64 * D, AsW + 2048);
    GLDS16(gsrc + 96 * D, AsW + 3072);
    __syncthreads();
    f32x4 cxr[8];
#pragma unroll
    for (int kk = 0; kk < 8; ++kk) cxr[kk] = *(const f32x4*)&cx[b][kc * 32 + kk * 4];
#pragma unroll
    for (int r = 0; r < 4; ++r) {
      const float* ap = As + (rq * 4 + r) * 32;
      float s = 0.f;
#pragma unroll
      for (int kk = 0; kk < 8; ++kk) {
        f32x4 a = *(const f32x4*)(ap + kk * 4);
        f32x4 c = cxr[kk];
        s += a[0] * c[0] + a[1] * c[1] + a[2] * c[2] + a[3] * c[3];
      }
      acc[r] += s;
    }
  }
#pragma unroll
  for (int r = 0; r < 4; ++r) {
    int R = RB * 128 + rq * 4 + r;
    float v = (acc[r] + bA[R]) * SCL;
    int n_u = R >> 8, k_u = R & 255;
    _Float16 hi = (_Float16)v;
    size_t o = ((size_t)(b * 256 + k_u)) * NU + n_u;  // k-major for stage-4 frags
    Uth[o] = hi;
    Utl[o] = (_Float16)(v - (float)hi);
  }
}

// Stage 4 v4: = v3 + T14 async eg-stage (prefetch next nc under the MFMA
// cluster) + s_setprio(1) around the MFMA cluster.
__global__ __launch_bounds__(512, 1) void k_logits(
    const float* __restrict__ eg, const _Float16* __restrict__ Uth,
    const _Float16* __restrict__ Utl, float* __restrict__ out)
{
  __shared__ _Float16 Ash[128 * 40];  // 128 v-rows x 32 n (padded)
  __shared__ _Float16 Asl[128 * 40];
  __shared__ float lacc[8][128];
  int tid = threadIdx.x;
  int v0 = blockIdx.x * 128;
  int lane = tid & 63, w = tid >> 6, nl = lane & 15, q = lane >> 4;
  int bh = w & 1, wk = w >> 1;   // batch half, k-slice
  for (int i = tid; i < 1024; i += 512) ((float*)lacc)[i] = 0.f;
  int sr = tid >> 2;          // 0..127 staged v-row
  int sc = (tid & 3) * 8;     // n offset
  int vr = v0 + sr;
  if (vr >= NV) vr = NV - 1;
  const float* asrc = eg + (size_t)vr * NU;
  f32x4 zero = {0, 0, 0, 0};
  // prologue: load nc=0 eg data (stage addresses are kg-independent)
  f32x4 u0 = *(const f32x4*)(asrc + sc);
  f32x4 u1 = *(const f32x4*)(asrc + sc + 4);
  __syncthreads();
  for (int kg = 0; kg < 4; ++kg) {
    f32x4 acc[4][8];  // [b'][mt]
#pragma unroll
    for (int b = 0; b < 4; ++b)
#pragma unroll
      for (int mt = 0; mt < 8; ++mt) acc[b][mt] = zero;
    for (int nc = 0; nc < 32; ++nc) {
      __syncthreads();
      {
        half8 h, l;
#pragma unroll
        for (int j = 0; j < 4; ++j) {
          float s0 = u0[j] * SCL;
          _Float16 h0 = (_Float16)s0;
          h[j] = h0; l[j] = (_Float16)(s0 - (float)h0);
          float s1 = u1[j] * SCL;
          _Float16 h1 = (_Float16)s1;
          h[j + 4] = h1; l[j + 4] = (_Float16)(s1 - (float)h1);
        }
        *(half8*)(Ash + sr * 40 + sc) = h;
        *(half8*)(Asl + sr * 40 + sc) = l;
      }
      // T14: issue next-nc eg loads now; s_waitcnt lands at next iteration's
      // convert (after this iteration's MFMA cluster) -> latency hidden.
      {
        int nnc = (nc + 1) & 31;
        const f32x4* np_ = (const f32x4*)(asrc + nnc * 32 + sc);
        u0 = np_[0];
        u1 = np_[1];
      }
      __syncthreads();
      half8 afh[8], afl[8];
#pragma unroll
      for (int mt = 0; mt < 8; ++mt) {
        afh[mt] = *(const half8*)(Ash + (mt * 16 + nl) * 40 + q * 8);
        afl[mt] = *(const half8*)(Asl + (mt * 16 + nl) * 40 + q * 8);
      }
      __builtin_amdgcn_s_setprio(1);
#pragma unroll
      for (int b = 0; b < 4; ++b) {
        int bb = bh * 4 + b;
        size_t o = ((size_t)(bb * 256 + kg * 64 + wk * 16 + nl)) * NU + nc * 32 + q * 8;
        half8 bfh = *(const half8*)(Uth + o);
        half8 bfl = *(const half8*)(Utl + o);
#pragma unroll
        for (int mt = 0; mt < 8; ++mt) {
          acc[b][mt] = __builtin_amdgcn_mfma_f32_16x16x32_f16(afh[mt], bfh, acc[b][mt], 0, 0, 0);
          acc[b][mt] = __builtin_amdgcn_mfma_f32_16x16x32_f16(afh[mt], bfl, acc[b][mt], 0, 0, 0);
          acc[b][mt] = __builtin_amdgcn_mfma_f32_16x16x32_f16(afl[mt], bfh, acc[b][mt], 0, 0, 0);
        }
      }
      __builtin_amdgcn_s_setprio(0);
    }
#pragma unroll
    for (int b = 0; b < 4; ++b) {
      int bb = bh * 4 + b;
#pragma unroll
      for (int mt = 0; mt < 8; ++mt) {
#pragma unroll
        for (int i = 0; i < 4; ++i) {
          float s = acc[b][mt][i] * acc[b][mt][i];
          s += __shfl_xor(s, 1);
          s += __shfl_xor(s, 2);
          s += __shfl_xor(s, 4);
          s += __shfl_xor(s, 8);
          if (nl == 0) atomicAdd(&lacc[bb][mt * 16 + q * 4 + i], s);
        }
      }
    }
  }
  __syncthreads();
  if (tid < 128) {
    int v = v0 + tid;
    if (v < NV) {
#pragma unroll
      for (int b = 0; b < 8; ++b) out[(size_t)b * NV + v] = lacc[b][tid] * ISCL4;
    }
  }
}

extern "C" void kernel_launch(void* const* d_in, const int* in_sizes, int n_in,
                              void* d_out, int out_size, void* d_ws, size_t ws_size,
                              hipStream_t stream)
{
  (void)in_sizes; (void)n_in; (void)out_size; (void)ws_size;
  const int* ids = (const int*)d_in[0];
  const float* emb = (const float*)d_in[1];
  const float* Wih = (const float*)d_in[2];
  const float* Whh = (const float*)d_in[3];
  const float* bih = (const float*)d_in[4];
  const float* bhh = (const float*)d_in[5];
  const float* WA = (const float*)d_in[6];
  const float* bA = (const float*)d_in[7];
  const float* eg = (const float*)d_in[8];
  float* out = (float*)d_out;

  char* ws = (char*)d_ws;
  size_t off = 0;
  auto take = [&](size_t bytes) -> char* {
    char* p = ws + off;
    off += (bytes + 255) & ~(size_t)255;
    return p;
  };
  float* gi32 = (float*)take((size_t)4096 * 3072 * 4);        // 50.3 MB
  char* xregion = take((size_t)4096 * 1024 * 2 * 2);          // x hi+lo 16.8 MB
  _Float16* xh = (_Float16*)xregion;
  _Float16* xl = xh + (size_t)4096 * 1024;
  _Float16* wh = (_Float16*)take((size_t)3072 * 1024 * 2);
  _Float16* wl = (_Float16*)take((size_t)3072 * 1024 * 2);
  unsigned* hrec = (unsigned*)take((size_t)2 * 4096 * 16);    // h record dbuf 128KB
  float* ctx = (float*)take((size_t)8 * 1024 * 4);
  // Ut aliases the x region (x dead after k_gi; Ut written by k_u afterwards)
  _Float16* Uth = (_Float16*)xregion;
  _Float16* Utl = Uth + (size_t)8 * 256 * 1024;

  k_prep<<<dim3(7168), dim3(256), 0, stream>>>(ids, emb, Wih, xh, xl, wh, wl);
  k_gi<<<dim3(32, 24), dim3(256), 0, stream>>>(xh, xl, wh, wl, bih, gi32);
  k_init<<<dim3(1), dim3(256), 0, stream>>>(hrec);
  k_gru<<<dim3(64), dim3(384), 0, stream>>>(Whh, gi32, bhh, hrec, ctx);
  k_u<<<dim3(2048), dim3(256), 0, stream>>>(WA, bA, ctx, Uth, Utl);
  k_logits<<<dim3(393), dim3(512), 0, stream>>>(eg, Uth, Utl, out);
}

// Round 11
// 3025.872 us; speedup vs baseline: 1.3352x; 1.0037x over previous
//
#include <hip/hip_runtime.h>

#define D 1024
#define G3 3072
#define NV 50257
#define NU 1024
#define KU 256
#define TOKROWS 4096
#define SCL 256.0f
#define ISCL2 (1.0f / 65536.0f)
#define ISCL4 (1.0f / 4294967296.0f)

typedef __attribute__((ext_vector_type(8))) _Float16 half8;
typedef __attribute__((ext_vector_type(4))) _Float16 half4;
typedef __attribute__((ext_vector_type(4))) float f32x4;
typedef __attribute__((ext_vector_type(4))) unsigned u32x4;

#define GLDS16(gp, lp) __builtin_amdgcn_global_load_lds( \
    (const __attribute__((address_space(1))) void*)(const void*)(gp), \
    (__attribute__((address_space(3))) void*)(void*)(lp), 16, 0, 0)

static __device__ __forceinline__ float sigmoidf_(float x) {
  return 1.0f / (1.0f + __expf(-x));
}
static __device__ __forceinline__ float tanhf_(float x) {
  float e = __expf(2.0f * x);
  return 1.0f - 2.0f / (e + 1.0f);
}

// Stage 0: gather x and convert W_ih to scaled hi/lo f16 pairs
__global__ __launch_bounds__(256) void k_prep(
    const int* __restrict__ ids, const float* __restrict__ emb,
    const float* __restrict__ Wih,
    _Float16* __restrict__ xh, _Float16* __restrict__ xl,
    _Float16* __restrict__ wh, _Float16* __restrict__ wl)
{
  int t = threadIdx.x;
  int wg = blockIdx.x;
  const float* src;
  _Float16 *dh, *dl;
  if (wg < TOKROWS) {
    src = emb + (size_t)ids[wg] * D;
    dh = xh + (size_t)wg * D; dl = xl + (size_t)wg * D;
  } else {
    int r = wg - TOKROWS;
    src = Wih + (size_t)r * D;
    dh = wh + (size_t)r * D; dl = wl + (size_t)r * D;
  }
  f32x4 v = ((const f32x4*)src)[t];
  half4 h, l;
#pragma unroll
  for (int j = 0; j < 4; ++j) {
    float vs = v[j] * SCL;
    _Float16 hi = (_Float16)vs;
    h[j] = hi;
    l[j] = (_Float16)(vs - (float)hi);
  }
  *(half4*)(dh + t * 4) = h;
  *(half4*)(dl + t * 4) = l;
}

// Stage 1 v2: gi = x @ W_ih^T + b_ih  (split-f16 MFMA, f32 out)
// K-step 64; linear GLDS dest + pre-swizzled global source + XOR frag read.
__global__ __launch_bounds__(256) void k_gi(
    const _Float16* __restrict__ Ah, const _Float16* __restrict__ Al,
    const _Float16* __restrict__ Bh, const _Float16* __restrict__ Bl,
    const float* __restrict__ bih, float* __restrict__ gi)
{
  __shared__ _Float16 Ash[128 * 64];
  __shared__ _Float16 Asl[128 * 64];
  __shared__ _Float16 Bsh[128 * 64];
  __shared__ _Float16 Bsl[128 * 64];
  int tid = threadIdx.x;
  int bm = blockIdx.x, bn = blockIdx.y;
  int lane = tid & 63, w = tid >> 6;
  int nl = lane & 15, q = lane >> 4;
  int wr = w >> 1, wc = w & 1;
  f32x4 zero = {0.f, 0.f, 0.f, 0.f};
  f32x4 acc[4][4];
#pragma unroll
  for (int i = 0; i < 4; i++)
#pragma unroll
    for (int j = 0; j < 4; j++) acc[i][j] = zero;
  int srow_in = tid >> 3;                       // 0..31
  int cg = ((tid & 7) ^ (srow_in & 7)) * 8;     // swizzled global col (f16)
  for (int kc = 0; kc < 16; ++kc) {
    __syncthreads();
#pragma unroll
    for (int s = 0; s < 4; ++s) {
      size_t go = ((size_t)(bm * 128 + s * 32 + srow_in)) * D + kc * 64 + cg;
      size_t go2 = ((size_t)(bn * 128 + s * 32 + srow_in)) * D + kc * 64 + cg;
      int lb = s * 2048 + w * 512;              // wave-uniform LDS base (f16)
      GLDS16(Ah + go, Ash + lb);
      GLDS16(Al + go, Asl + lb);
      GLDS16(Bh + go2, Bsh + lb);
      GLDS16(Bl + go2, Bsl + lb);
    }
    __syncthreads();
    half8 afh[4][2], afl[4][2], bfh[4][2], bfl[4][2];
#pragma unroll
    for (int mt = 0; mt < 4; ++mt) {
      int R = wr * 64 + mt * 16 + nl;
#pragma unroll
      for (int kt = 0; kt < 2; ++kt) {
        int o = R * 64 + ((kt * 4 + q) ^ (R & 7)) * 8;
        afh[mt][kt] = *(const half8*)(Ash + o);
        afl[mt][kt] = *(const half8*)(Asl + o);
      }
    }
#pragma unroll
    for (int nt = 0; nt < 4; ++nt) {
      int R = wc * 64 + nt * 16 + nl;
#pragma unroll
      for (int kt = 0; kt < 2; ++kt) {
        int o = R * 64 + ((kt * 4 + q) ^ (R & 7)) * 8;
        bfh[nt][kt] = *(const half8*)(Bsh + o);
        bfl[nt][kt] = *(const half8*)(Bsl + o);
      }
    }
#pragma unroll
    for (int mt = 0; mt < 4; ++mt)
#pragma unroll
      for (int nt = 0; nt < 4; ++nt)
#pragma unroll
        for (int kt = 0; kt < 2; ++kt) {
          acc[mt][nt] = __builtin_amdgcn_mfma_f32_16x16x32_f16(afh[mt][kt], bfh[nt][kt], acc[mt][nt], 0, 0, 0);
          acc[mt][nt] = __builtin_amdgcn_mfma_f32_16x16x32_f16(afh[mt][kt], bfl[nt][kt], acc[mt][nt], 0, 0, 0);
          acc[mt][nt] = __builtin_amdgcn_mfma_f32_16x16x32_f16(afl[mt][kt], bfh[nt][kt], acc[mt][nt], 0, 0, 0);
        }
  }
#pragma unroll
  for (int mt = 0; mt < 4; ++mt)
#pragma unroll
    for (int nt = 0; nt < 4; ++nt) {
      int col = bn * 128 + wc * 64 + nt * 16 + nl;
      float bv = bih[col];
#pragma unroll
      for (int i = 0; i < 4; i++) {
        int row = bm * 128 + wr * 64 + mt * 16 + q * 4 + i;
        gi[(size_t)row * G3 + col] = acc[mt][nt][i] * ISCL2 + bv;
      }
    }
}

// init: zero the h-record double buffer (2 x 4096 records x 16B); tags become 0,
// which is exactly what step 0 polls for (h(0)=0). Must run every launch (replay).
__global__ void k_init(unsigned* __restrict__ rec32)
{
  int t = threadIdx.x;
  for (int i = t; i < 32768; i += 256) rec32[i] = 0u;
}

// Stage 2 (R6-proven, frozen): GRU scan, 64 WGs x 6 waves. h exchanged as 16B
// records {pkh, pkl, tag, pad}; tag rides with the data (dataflow barrier,
// exact-tag match is skew-safe); bulk load + per-chunk tag-verify IS the poll.
__global__ __launch_bounds__(384) void k_gru(
    const float* __restrict__ Whh, const float* __restrict__ gi,
    const float* __restrict__ bhh, unsigned* __restrict__ hrec,
    float* __restrict__ ctx)
{
  int tid = threadIdx.x;
  int wid = blockIdx.x;           // 64 WGs, d-slice of 16 each
  int w = tid >> 6;               // 6 waves
  int g = w >> 1;                 // gate: 0=r 1=z 2=n
  int kh = w & 1;                 // K half (512 each)
  int lane = tid & 63, nl = lane & 15, q = lane >> 4;
  __shared__ _Float16 hs[16 * 1024];   // unpacked h (32 KB), 16B-chunk XOR swizzle
  __shared__ float gp[6][3][8][17];    // [wave][slot][batch][d] partials

  // W_hh slice -> registers, scaled hi/lo f16 B-fragments
  half8 bwh[16], bwl[16];
  {
    const float* wrow = Whh + ((size_t)(g * 1024 + wid * 16 + nl)) * D + kh * 512;
#pragma unroll
    for (int kt = 0; kt < 16; ++kt) {
      const f32x4* p = (const f32x4*)(wrow + kt * 32 + q * 8);
      f32x4 v0 = p[0], v1 = p[1];
      half8 h, l;
#pragma unroll
      for (int j = 0; j < 4; ++j) {
        float s0 = v0[j] * SCL;
        _Float16 h0 = (_Float16)s0;
        h[j] = h0; l[j] = (_Float16)(s0 - (float)h0);
        float s1 = v1[j] * SCL;
        _Float16 h1 = (_Float16)s1;
        h[j + 4] = h1; l[j + 4] = (_Float16)(s1 - (float)h1);
      }
      bwh[kt] = h; bwl[kt] = l;
    }
  }

  // update-role state (wave 0): each thread owns (batch m, dims d0,d0+1)
  int m = tid >> 3, np = (tid & 7) * 2;
  int d0 = wid * 16 + np;
  float hr0 = 0.f, hr1 = 0.f;
  float bh[6] = {0, 0, 0, 0, 0, 0};
  if (tid < 64) {
#pragma unroll
    for (int gg = 0; gg < 3; ++gg) {
      bh[gg * 2] = bhh[gg * 1024 + d0];
      bh[gg * 2 + 1] = bhh[gg * 1024 + d0 + 1];
    }
  }
  f32x4 zero = {0, 0, 0, 0};

  for (int step = 0; step < 512; ++step) {
    float gi6[6] = {0, 0, 0, 0, 0, 0};
    if (tid < 64) {  // gi for this step (f32, plain cached loads; drain in poll)
      const float* gpt = gi + ((size_t)(m * 512 + step)) * G3 + d0;
#pragma unroll
      for (int gg = 0; gg < 3; ++gg) {
        gi6[gg * 2] = gpt[gg * 1024];
        gi6[gg * 2 + 1] = gpt[gg * 1024 + 1];
      }
    }

    // ---- poll h records (tag == step) and unpack into LDS ----
    {
      unsigned want = (unsigned)step;
      const u32x4* rb = (const u32x4*)hrec + (size_t)(step & 1) * 4096;
      u32x4 rv[11];
      unsigned need = 0;
#pragma unroll
      for (int k = 0; k < 11; ++k) {
        int r = tid + k * 384;
        if (r < 4096) need |= (1u << k);
      }
      while (need) {
        unsigned mm = need;
#pragma unroll
        for (int k = 0; k < 11; ++k)
          if (mm & (1u << k)) {
            int r = tid + k * 384;
            asm volatile("global_load_dwordx4 %0, %1, off sc0 sc1"
                         : "=v"(rv[k]) : "v"(rb + r));
          }
        asm volatile("s_waitcnt vmcnt(0)" ::: "memory");
#pragma unroll
        for (int k = 0; k < 11; ++k)
          if ((mm & (1u << k)) && rv[k][2] == want) need &= ~(1u << k);
      }
      __builtin_amdgcn_sched_barrier(0);
#pragma unroll
      for (int k = 0; k < 11; ++k) {
        int r = tid + k * 384;
        if (r < 4096) {
          int w2 = r >> 6, l2 = r & 63;
          int m2 = l2 >> 3;
          int d = (w2 << 4) + ((l2 & 7) << 1);
          int chunk = d >> 3, wi = d & 7;
          int sw = chunk ^ (m2 & 7);
          *(unsigned*)&hs[((m2 * 128 + sw) << 3) + wi] = rv[k][0];          // hi row
          *(unsigned*)&hs[(((m2 + 8) * 128 + sw) << 3) + wi] = rv[k][1];    // lo row
        }
      }
    }
    __syncthreads();  // #A: staged h visible

    // A fragments from LDS (swizzled chunks), then MFMA
    half8 av[16];
#pragma unroll
    for (int kt = 0; kt < 16; ++kt) {
      int chunk = kh * 64 + kt * 4 + q;
      av[kt] = *(const half8*)&hs[(size_t)(nl * 128 + (chunk ^ (nl & 7))) * 8];
    }
    f32x4 ac1 = zero, ac2 = zero;
#pragma unroll
    for (int kt = 0; kt < 16; ++kt) {
      ac1 = __builtin_amdgcn_mfma_f32_16x16x32_f16(av[kt], bwh[kt], ac1, 0, 0, 0);
      ac2 = __builtin_amdgcn_mfma_f32_16x16x32_f16(av[kt], bwl[kt], ac2, 0, 0, 0);
    }
    // partials: slot0 = hi@Wh (rows 0-7), slot1 = lo@Wh (rows 8-15), slot2 = hi@Wl
    if (q < 2) {
#pragma unroll
      for (int i = 0; i < 4; i++) {
        gp[w][0][q * 4 + i][nl] = ac1[i];
        gp[w][2][q * 4 + i][nl] = ac2[i];
      }
    } else {
#pragma unroll
      for (int i = 0; i < 4; i++) gp[w][1][(q - 2) * 4 + i][nl] = ac1[i];
    }
    __syncthreads();  // #B: partials visible to wave 0
    if (tid < 64) {
      float gh[6];
#pragma unroll
      for (int g2 = 0; g2 < 3; ++g2) {
        float s0 = 0.f, s1 = 0.f;
#pragma unroll
        for (int k2 = 0; k2 < 2; ++k2) {
          int wv = g2 * 2 + k2;
#pragma unroll
          for (int s = 0; s < 3; ++s) {
            s0 += gp[wv][s][m][np];
            s1 += gp[wv][s][m][np + 1];
          }
        }
        gh[g2 * 2] = s0 * ISCL2;
        gh[g2 * 2 + 1] = s1 * ISCL2;
      }
      float r0_ = sigmoidf_(gi6[0] + gh[0] + bh[0]);
      float r1_ = sigmoidf_(gi6[1] + gh[1] + bh[1]);
      float z0_ = sigmoidf_(gi6[2] + gh[2] + bh[2]);
      float z1_ = sigmoidf_(gi6[3] + gh[3] + bh[3]);
      float n0_ = tanhf_(gi6[4] + r0_ * (gh[4] + bh[4]));
      float n1_ = tanhf_(gi6[5] + r1_ * (gh[5] + bh[5]));
      float h0_ = (1.f - z0_) * n0_ + z0_ * hr0;
      float h1_ = (1.f - z1_) * n1_ + z1_ * hr1;
      hr0 = h0_; hr1 = h1_;
      float s0 = h0_ * SCL, s1 = h1_ * SCL;
      _Float16 h0h = (_Float16)s0, h1h = (_Float16)s1;
      _Float16 h0l = (_Float16)(s0 - (float)h0h), h1l = (_Float16)(s1 - (float)h1h);
      u32x4 rec;
      rec[0] = (unsigned)__builtin_bit_cast(unsigned short, h0h) |
               ((unsigned)__builtin_bit_cast(unsigned short, h1h) << 16);
      rec[1] = (unsigned)__builtin_bit_cast(unsigned short, h0l) |
               ((unsigned)__builtin_bit_cast(unsigned short, h1l) << 16);
      rec[2] = (unsigned)(step + 1);
      rec[3] = 0u;
      u32x4* dst = (u32x4*)hrec + ((size_t)((step + 1) & 1) * 4096 + wid * 64 + tid);
      asm volatile("global_store_dwordx4 %0, %1, off sc0 sc1"
                   :: "v"(dst), "v"(rec) : "memory");
      if (step == 511) {
        ctx[m * D + d0] = h0_;
        ctx[m * D + d0 + 1] = h1_;
      }
    }
    // no third barrier: next step's poll is the dataflow barrier
  }
}

// Stage 3: U = ctx @ W_A^T + b_A  (f32 VALU, BW-bound); scaled hi/lo out
__global__ __launch_bounds__(256) void k_u(
    const float* __restrict__ WA, const float* __restrict__ bA,
    const float* __restrict__ ctx, _Float16* __restrict__ Uth,
    _Float16* __restrict__ Utl)
{
  __shared__ float As[128 * 32];
  __shared__ float cx[8][1032];
  int tid = threadIdx.x;
  int RB = blockIdx.x;  // 2048 blocks x 128 rows
#pragma unroll
  for (int jj = 0; jj < 8; ++jj) {
    int e = tid * 32 + jj * 4;
    *(f32x4*)&cx[e >> 10][e & 1023] = *(const f32x4*)(ctx + e);
  }
  float acc[4] = {0.f, 0.f, 0.f, 0.f};
  int b = tid & 7, rq = tid >> 3;
  float* AsW = As + (tid >> 6) * 256;  // wave-uniform staging base (1KB)
  int sr = tid >> 3;
  int sc = (tid & 7) * 4;
  __syncthreads();
  for (int kc = 0; kc < 32; ++kc) {
    __syncthreads();
    const float* gsrc = WA + ((size_t)(RB * 128 + sr)) * D + kc * 32 + sc;
    GLDS16(gsrc, AsW);
    GLDS16(gsrc + 32 * D, AsW + 1024);
    GLDS16(gsrc + 64 * D, AsW + 2048);
    GLDS16(gsrc + 96 * D, AsW + 3072);
    __syncthreads();
    f32x4 cxr[8];
#pragma unroll
    for (int kk = 0; kk < 8; ++kk) cxr[kk] = *(const f32x4*)&cx[b][kc * 32 + kk * 4];
#pragma unroll
    for (int r = 0; r < 4; ++r) {
      const float* ap = As + (rq * 4 + r) * 32;
      float s = 0.f;
#pragma unroll
      for (int kk = 0; kk < 8; ++kk) {
        f32x4 a = *(const f32x4*)(ap + kk * 4);
        f32x4 c = cxr[kk];
        s += a[0] * c[0] + a[1] * c[1] + a[2] * c[2] + a[3] * c[3];
      }
      acc[r] += s;
    }
  }
#pragma unroll
  for (int r = 0; r < 4; ++r) {
    int R = RB * 128 + rq * 4 + r;
    float v = (acc[r] + bA[R]) * SCL;
    int n_u = R >> 8, k_u = R & 255;
    _Float16 hi = (_Float16)v;
    size_t o = ((size_t)(b * 256 + k_u)) * NU + n_u;  // k-major for stage-4 frags
    Uth[o] = hi;
    Utl[o] = (_Float16)(v - (float)hi);
  }
}

// Stage 4 v5: single-barrier LDS double-buffer. At iter t: read buf[t&1],
// write buf[(t+1)&1] (next nc, from regs prefetched at t-1), prefetch t+2,
// MFMA (setprio), ONE barrier. eg prefetch gets the whole MFMA window to land.
__global__ __launch_bounds__(512, 1) void k_logits(
    const float* __restrict__ eg, const _Float16* __restrict__ Uth,
    const _Float16* __restrict__ Utl, float* __restrict__ out)
{
  __shared__ _Float16 Ash[2][128 * 40];  // dbuf: 128 v-rows x 32 n (padded)
  __shared__ _Float16 Asl[2][128 * 40];
  __shared__ float lacc[8][128];
  int tid = threadIdx.x;
  int v0 = blockIdx.x * 128;
  int lane = tid & 63, w = tid >> 6, nl = lane & 15, q = lane >> 4;
  int bh = w & 1, wk = w >> 1;   // batch half, k-slice
  for (int i = tid; i < 1024; i += 512) ((float*)lacc)[i] = 0.f;
  int sr = tid >> 2;          // 0..127 staged v-row
  int sc = (tid & 3) * 8;     // n offset
  int vr = v0 + sr;
  if (vr >= NV) vr = NV - 1;
  const float* asrc = eg + (size_t)vr * NU;
  f32x4 zero = {0, 0, 0, 0};
  // prologue: stage nc=0 into buf0; prefetch nc=1 into regs
  {
    f32x4 a0 = *(const f32x4*)(asrc + sc);
    f32x4 a1 = *(const f32x4*)(asrc + sc + 4);
    half8 h, l;
#pragma unroll
    for (int j = 0; j < 4; ++j) {
      float s0 = a0[j] * SCL;
      _Float16 h0 = (_Float16)s0;
      h[j] = h0; l[j] = (_Float16)(s0 - (float)h0);
      float s1 = a1[j] * SCL;
      _Float16 h1 = (_Float16)s1;
      h[j + 4] = h1; l[j + 4] = (_Float16)(s1 - (float)h1);
    }
    *(half8*)(&Ash[0][sr * 40 + sc]) = h;
    *(half8*)(&Asl[0][sr * 40 + sc]) = l;
  }
  f32x4 u0 = *(const f32x4*)(asrc + 32 + sc);
  f32x4 u1 = *(const f32x4*)(asrc + 32 + sc + 4);
  __syncthreads();
  int t = 0;
  for (int kg = 0; kg < 4; ++kg) {
    f32x4 acc[4][8];  // [b'][mt]
#pragma unroll
    for (int b = 0; b < 4; ++b)
#pragma unroll
      for (int mt = 0; mt < 8; ++mt) acc[b][mt] = zero;
    for (int nc = 0; nc < 32; ++nc, ++t) {
      int p = t & 1;
      // write NEXT iteration's A-tile into the other buffer
      {
        half8 h, l;
#pragma unroll
        for (int j = 0; j < 4; ++j) {
          float s0 = u0[j] * SCL;
          _Float16 h0 = (_Float16)s0;
          h[j] = h0; l[j] = (_Float16)(s0 - (float)h0);
          float s1 = u1[j] * SCL;
          _Float16 h1 = (_Float16)s1;
          h[j + 4] = h1; l[j + 4] = (_Float16)(s1 - (float)h1);
        }
        *(half8*)(&Ash[p ^ 1][sr * 40 + sc]) = h;
        *(half8*)(&Asl[p ^ 1][sr * 40 + sc]) = l;
      }
      // prefetch for iter t+2 (nc wraps across kg; data is kg-independent)
      {
        int nn = (nc + 2) & 31;
        const f32x4* np_ = (const f32x4*)(asrc + nn * 32 + sc);
        u0 = np_[0];
        u1 = np_[1];
      }
      // read this iteration's frags from buf[p]
      half8 afh[8], afl[8];
#pragma unroll
      for (int mt = 0; mt < 8; ++mt) {
        afh[mt] = *(const half8*)(&Ash[p][(mt * 16 + nl) * 40 + q * 8]);
        afl[mt] = *(const half8*)(&Asl[p][(mt * 16 + nl) * 40 + q * 8]);
      }
      __builtin_amdgcn_s_setprio(1);
#pragma unroll
      for (int b = 0; b < 4; ++b) {
        int bb = bh * 4 + b;
        size_t o = ((size_t)(bb * 256 + kg * 64 + wk * 16 + nl)) * NU + nc * 32 + q * 8;
        half8 bfh = *(const half8*)(Uth + o);
        half8 bfl = *(const half8*)(Utl + o);
#pragma unroll
        for (int mt = 0; mt < 8; ++mt) {
          acc[b][mt] = __builtin_amdgcn_mfma_f32_16x16x32_f16(afh[mt], bfh, acc[b][mt], 0, 0, 0);
          acc[b][mt] = __builtin_amdgcn_mfma_f32_16x16x32_f16(afh[mt], bfl, acc[b][mt], 0, 0, 0);
          acc[b][mt] = __builtin_amdgcn_mfma_f32_16x16x32_f16(afl[mt], bfh, acc[b][mt], 0, 0, 0);
        }
      }
      __builtin_amdgcn_s_setprio(0);
      __syncthreads();  // single barrier: separates buf writes/reads across iters
    }
#pragma unroll
    for (int b = 0; b < 4; ++b) {
      int bb = bh * 4 + b;
#pragma unroll
      for (int mt = 0; mt < 8; ++mt) {
#pragma unroll
        for (int i = 0; i < 4; ++i) {
          float s = acc[b][mt][i] * acc[b][mt][i];
          s += __shfl_xor(s, 1);
          s += __shfl_xor(s, 2);
          s += __shfl_xor(s, 4);
          s += __shfl_xor(s, 8);
          if (nl == 0) atomicAdd(&lacc[bb][mt * 16 + q * 4 + i], s);
        }
      }
    }
  }
  __syncthreads();
  if (tid < 128) {
    int v = v0 + tid;
    if (v < NV) {
#pragma unroll
      for (int b = 0; b < 8; ++b) out[(size_t)b * NV + v] = lacc[b][tid] * ISCL4;
    }
  }
}

extern "C" void kernel_launch(void* const* d_in, const int* in_sizes, int n_in,
                              void* d_out, int out_size, void* d_ws, size_t ws_size,
                              hipStream_t stream)
{
  (void)in_sizes; (void)n_in; (void)out_size; (void)ws_size;
  const int* ids = (const int*)d_in[0];
  const float* emb = (const float*)d_in[1];
  const float* Wih = (const float*)d_in[2];
  const float* Whh = (const float*)d_in[3];
  const float* bih = (const float*)d_in[4];
  const float* bhh = (const float*)d_in[5];
  const float* WA = (const float*)d_in[6];
  const float* bA = (const float*)d_in[7];
  const float* eg = (const float*)d_in[8];
  float* out = (float*)d_out;

  char* ws = (char*)d_ws;
  size_t off = 0;
  auto take = [&](size_t bytes) -> char* {
    char* p = ws + off;
    off += (bytes + 255) & ~(size_t)255;
    return p;
  };
  float* gi32 = (float*)take((size_t)4096 * 3072 * 4);        // 50.3 MB
  char* xregion = take((size_t)4096 * 1024 * 2 * 2);          // x hi+lo 16.8 MB
  _Float16* xh = (_Float16*)xregion;
  _Float16* xl = xh + (size_t)4096 * 1024;
  _Float16* wh = (_Float16*)take((size_t)3072 * 1024 * 2);
  _Float16* wl = (_Float16*)take((size_t)3072 * 1024 * 2);
  unsigned* hrec = (unsigned*)take((size_t)2 * 4096 * 16);    // h record dbuf 128KB
  float* ctx = (float*)take((size_t)8 * 1024 * 4);
  // Ut aliases the x region (x dead after k_gi; Ut written by k_u afterwards)
  _Float16* Uth = (_Float16*)xregion;
  _Float16* Utl = Uth + (size_t)8 * 256 * 1024;

  k_prep<<<dim3(7168), dim3(256), 0, stream>>>(ids, emb, Wih, xh, xl, wh, wl);
  k_gi<<<dim3(32, 24), dim3(256), 0, stream>>>(xh, xl, wh, wl, bih, gi32);
  k_init<<<dim3(1), dim3(256), 0, stream>>>(hrec);
  k_gru<<<dim3(64), dim3(384), 0, stream>>>(Whh, gi32, bhh, hrec, ctx);
  k_u<<<dim3(2048), dim3(256), 0, stream>>>(WA, bA, ctx, Uth, Utl);
  k_logits<<<dim3(393), dim3(512), 0, stream>>>(eg, Uth, Utl, out);
}

// Round 12
// 2960.858 us; speedup vs baseline: 1.3645x; 1.0220x over previous
//
#include <hip/hip_runtime.h>

#define D 1024
#define G3 3072
#define NV 50257
#define NU 1024
#define KU 256
#define TOKROWS 4096
#define SCL 256.0f
#define ISCL2 (1.0f / 65536.0f)
#define ISCL4 (1.0f / 4294967296.0f)

typedef __attribute__((ext_vector_type(8))) _Float16 half8;
typedef __attribute__((ext_vector_type(4))) _Float16 half4;
typedef __attribute__((ext_vector_type(4))) float f32x4;
typedef __attribute__((ext_vector_type(4))) unsigned u32x4;

#define GLDS16(gp, lp) __builtin_amdgcn_global_load_lds( \
    (const __attribute__((address_space(1))) void*)(const void*)(gp), \
    (__attribute__((address_space(3))) void*)(void*)(lp), 16, 0, 0)

static __device__ __forceinline__ float sigmoidf_(float x) {
  return 1.0f / (1.0f + __expf(-x));
}
static __device__ __forceinline__ float tanhf_(float x) {
  float e = __expf(2.0f * x);
  return 1.0f - 2.0f / (e + 1.0f);
}

// Stage 0: gather x and convert W_ih to scaled hi/lo f16 pairs
__global__ __launch_bounds__(256) void k_prep(
    const int* __restrict__ ids, const float* __restrict__ emb,
    const float* __restrict__ Wih,
    _Float16* __restrict__ xh, _Float16* __restrict__ xl,
    _Float16* __restrict__ wh, _Float16* __restrict__ wl)
{
  int t = threadIdx.x;
  int wg = blockIdx.x;
  const float* src;
  _Float16 *dh, *dl;
  if (wg < TOKROWS) {
    src = emb + (size_t)ids[wg] * D;
    dh = xh + (size_t)wg * D; dl = xl + (size_t)wg * D;
  } else {
    int r = wg - TOKROWS;
    src = Wih + (size_t)r * D;
    dh = wh + (size_t)r * D; dl = wl + (size_t)r * D;
  }
  f32x4 v = ((const f32x4*)src)[t];
  half4 h, l;
#pragma unroll
  for (int j = 0; j < 4; ++j) {
    float vs = v[j] * SCL;
    _Float16 hi = (_Float16)vs;
    h[j] = hi;
    l[j] = (_Float16)(vs - (float)hi);
  }
  *(half4*)(dh + t * 4) = h;
  *(half4*)(dl + t * 4) = l;
}

// Stage 1 v2: gi = x @ W_ih^T + b_ih  (split-f16 MFMA, f32 out)
// K-step 64; linear GLDS dest + pre-swizzled global source + XOR frag read.
__global__ __launch_bounds__(256) void k_gi(
    const _Float16* __restrict__ Ah, const _Float16* __restrict__ Al,
    const _Float16* __restrict__ Bh, const _Float16* __restrict__ Bl,
    const float* __restrict__ bih, float* __restrict__ gi)
{
  __shared__ _Float16 Ash[128 * 64];
  __shared__ _Float16 Asl[128 * 64];
  __shared__ _Float16 Bsh[128 * 64];
  __shared__ _Float16 Bsl[128 * 64];
  int tid = threadIdx.x;
  int bm = blockIdx.x, bn = blockIdx.y;
  int lane = tid & 63, w = tid >> 6;
  int nl = lane & 15, q = lane >> 4;
  int wr = w >> 1, wc = w & 1;
  f32x4 zero = {0.f, 0.f, 0.f, 0.f};
  f32x4 acc[4][4];
#pragma unroll
  for (int i = 0; i < 4; i++)
#pragma unroll
    for (int j = 0; j < 4; j++) acc[i][j] = zero;
  int srow_in = tid >> 3;                       // 0..31
  int cg = ((tid & 7) ^ (srow_in & 7)) * 8;     // swizzled global col (f16)
  for (int kc = 0; kc < 16; ++kc) {
    __syncthreads();
#pragma unroll
    for (int s = 0; s < 4; ++s) {
      size_t go = ((size_t)(bm * 128 + s * 32 + srow_in)) * D + kc * 64 + cg;
      size_t go2 = ((size_t)(bn * 128 + s * 32 + srow_in)) * D + kc * 64 + cg;
      int lb = s * 2048 + w * 512;              // wave-uniform LDS base (f16)
      GLDS16(Ah + go, Ash + lb);
      GLDS16(Al + go, Asl + lb);
      GLDS16(Bh + go2, Bsh + lb);
      GLDS16(Bl + go2, Bsl + lb);
    }
    __syncthreads();
    half8 afh[4][2], afl[4][2], bfh[4][2], bfl[4][2];
#pragma unroll
    for (int mt = 0; mt < 4; ++mt) {
      int R = wr * 64 + mt * 16 + nl;
#pragma unroll
      for (int kt = 0; kt < 2; ++kt) {
        int o = R * 64 + ((kt * 4 + q) ^ (R & 7)) * 8;
        afh[mt][kt] = *(const half8*)(Ash + o);
        afl[mt][kt] = *(const half8*)(Asl + o);
      }
    }
#pragma unroll
    for (int nt = 0; nt < 4; ++nt) {
      int R = wc * 64 + nt * 16 + nl;
#pragma unroll
      for (int kt = 0; kt < 2; ++kt) {
        int o = R * 64 + ((kt * 4 + q) ^ (R & 7)) * 8;
        bfh[nt][kt] = *(const half8*)(Bsh + o);
        bfl[nt][kt] = *(const half8*)(Bsl + o);
      }
    }
#pragma unroll
    for (int mt = 0; mt < 4; ++mt)
#pragma unroll
      for (int nt = 0; nt < 4; ++nt)
#pragma unroll
        for (int kt = 0; kt < 2; ++kt) {
          acc[mt][nt] = __builtin_amdgcn_mfma_f32_16x16x32_f16(afh[mt][kt], bfh[nt][kt], acc[mt][nt], 0, 0, 0);
          acc[mt][nt] = __builtin_amdgcn_mfma_f32_16x16x32_f16(afh[mt][kt], bfl[nt][kt], acc[mt][nt], 0, 0, 0);
          acc[mt][nt] = __builtin_amdgcn_mfma_f32_16x16x32_f16(afl[mt][kt], bfh[nt][kt], acc[mt][nt], 0, 0, 0);
        }
  }
#pragma unroll
  for (int mt = 0; mt < 4; ++mt)
#pragma unroll
    for (int nt = 0; nt < 4; ++nt) {
      int col = bn * 128 + wc * 64 + nt * 16 + nl;
      float bv = bih[col];
#pragma unroll
      for (int i = 0; i < 4; i++) {
        int row = bm * 128 + wr * 64 + mt * 16 + q * 4 + i;
        gi[(size_t)row * G3 + col] = acc[mt][nt][i] * ISCL2 + bv;
      }
    }
}

// init: zero the h-record double buffer (2 x 4096 records x 16B); tags become 0,
// which is exactly what step 0 polls for (h(0)=0). Must run every launch (replay).
__global__ void k_init(unsigned* __restrict__ rec32)
{
  int t = threadIdx.x;
  for (int i = t; i < 32768; i += 256) rec32[i] = 0u;
}

// Stage 2 (R6-proven, frozen): GRU scan, 64 WGs x 6 waves. h exchanged as 16B
// records {pkh, pkl, tag, pad}; tag rides with the data (dataflow barrier,
// exact-tag match is skew-safe); bulk load + per-chunk tag-verify IS the poll.
__global__ __launch_bounds__(384) void k_gru(
    const float* __restrict__ Whh, const float* __restrict__ gi,
    const float* __restrict__ bhh, unsigned* __restrict__ hrec,
    float* __restrict__ ctx)
{
  int tid = threadIdx.x;
  int wid = blockIdx.x;           // 64 WGs, d-slice of 16 each
  int w = tid >> 6;               // 6 waves
  int g = w >> 1;                 // gate: 0=r 1=z 2=n
  int kh = w & 1;                 // K half (512 each)
  int lane = tid & 63, nl = lane & 15, q = lane >> 4;
  __shared__ _Float16 hs[16 * 1024];   // unpacked h (32 KB), 16B-chunk XOR swizzle
  __shared__ float gp[6][3][8][17];    // [wave][slot][batch][d] partials

  // W_hh slice -> registers, scaled hi/lo f16 B-fragments
  half8 bwh[16], bwl[16];
  {
    const float* wrow = Whh + ((size_t)(g * 1024 + wid * 16 + nl)) * D + kh * 512;
#pragma unroll
    for (int kt = 0; kt < 16; ++kt) {
      const f32x4* p = (const f32x4*)(wrow + kt * 32 + q * 8);
      f32x4 v0 = p[0], v1 = p[1];
      half8 h, l;
#pragma unroll
      for (int j = 0; j < 4; ++j) {
        float s0 = v0[j] * SCL;
        _Float16 h0 = (_Float16)s0;
        h[j] = h0; l[j] = (_Float16)(s0 - (float)h0);
        float s1 = v1[j] * SCL;
        _Float16 h1 = (_Float16)s1;
        h[j + 4] = h1; l[j + 4] = (_Float16)(s1 - (float)h1);
      }
      bwh[kt] = h; bwl[kt] = l;
    }
  }

  // update-role state (wave 0): each thread owns (batch m, dims d0,d0+1)
  int m = tid >> 3, np = (tid & 7) * 2;
  int d0 = wid * 16 + np;
  float hr0 = 0.f, hr1 = 0.f;
  float bh[6] = {0, 0, 0, 0, 0, 0};
  if (tid < 64) {
#pragma unroll
    for (int gg = 0; gg < 3; ++gg) {
      bh[gg * 2] = bhh[gg * 1024 + d0];
      bh[gg * 2 + 1] = bhh[gg * 1024 + d0 + 1];
    }
  }
  f32x4 zero = {0, 0, 0, 0};

  for (int step = 0; step < 512; ++step) {
    float gi6[6] = {0, 0, 0, 0, 0, 0};
    if (tid < 64) {  // gi for this step (f32, plain cached loads; drain in poll)
      const float* gpt = gi + ((size_t)(m * 512 + step)) * G3 + d0;
#pragma unroll
      for (int gg = 0; gg < 3; ++gg) {
        gi6[gg * 2] = gpt[gg * 1024];
        gi6[gg * 2 + 1] = gpt[gg * 1024 + 1];
      }
    }

    // ---- poll h records (tag == step) and unpack into LDS ----
    {
      unsigned want = (unsigned)step;
      const u32x4* rb = (const u32x4*)hrec + (size_t)(step & 1) * 4096;
      u32x4 rv[11];
      unsigned need = 0;
#pragma unroll
      for (int k = 0; k < 11; ++k) {
        int r = tid + k * 384;
        if (r < 4096) need |= (1u << k);
      }
      while (need) {
        unsigned mm = need;
#pragma unroll
        for (int k = 0; k < 11; ++k)
          if (mm & (1u << k)) {
            int r = tid + k * 384;
            asm volatile("global_load_dwordx4 %0, %1, off sc0 sc1"
                         : "=v"(rv[k]) : "v"(rb + r));
          }
        asm volatile("s_waitcnt vmcnt(0)" ::: "memory");
#pragma unroll
        for (int k = 0; k < 11; ++k)
          if ((mm & (1u << k)) && rv[k][2] == want) need &= ~(1u << k);
      }
      __builtin_amdgcn_sched_barrier(0);
#pragma unroll
      for (int k = 0; k < 11; ++k) {
        int r = tid + k * 384;
        if (r < 4096) {
          int w2 = r >> 6, l2 = r & 63;
          int m2 = l2 >> 3;
          int d = (w2 << 4) + ((l2 & 7) << 1);
          int chunk = d >> 3, wi = d & 7;
          int sw = chunk ^ (m2 & 7);
          *(unsigned*)&hs[((m2 * 128 + sw) << 3) + wi] = rv[k][0];          // hi row
          *(unsigned*)&hs[(((m2 + 8) * 128 + sw) << 3) + wi] = rv[k][1];    // lo row
        }
      }
    }
    __syncthreads();  // #A: staged h visible

    // A fragments from LDS (swizzled chunks), then MFMA
    half8 av[16];
#pragma unroll
    for (int kt = 0; kt < 16; ++kt) {
      int chunk = kh * 64 + kt * 4 + q;
      av[kt] = *(const half8*)&hs[(size_t)(nl * 128 + (chunk ^ (nl & 7))) * 8];
    }
    f32x4 ac1 = zero, ac2 = zero;
#pragma unroll
    for (int kt = 0; kt < 16; ++kt) {
      ac1 = __builtin_amdgcn_mfma_f32_16x16x32_f16(av[kt], bwh[kt], ac1, 0, 0, 0);
      ac2 = __builtin_amdgcn_mfma_f32_16x16x32_f16(av[kt], bwl[kt], ac2, 0, 0, 0);
    }
    // partials: slot0 = hi@Wh (rows 0-7), slot1 = lo@Wh (rows 8-15), slot2 = hi@Wl
    if (q < 2) {
#pragma unroll
      for (int i = 0; i < 4; i++) {
        gp[w][0][q * 4 + i][nl] = ac1[i];
        gp[w][2][q * 4 + i][nl] = ac2[i];
      }
    } else {
#pragma unroll
      for (int i = 0; i < 4; i++) gp[w][1][(q - 2) * 4 + i][nl] = ac1[i];
    }
    __syncthreads();  // #B: partials visible to wave 0
    if (tid < 64) {
      float gh[6];
#pragma unroll
      for (int g2 = 0; g2 < 3; ++g2) {
        float s0 = 0.f, s1 = 0.f;
#pragma unroll
        for (int k2 = 0; k2 < 2; ++k2) {
          int wv = g2 * 2 + k2;
#pragma unroll
          for (int s = 0; s < 3; ++s) {
            s0 += gp[wv][s][m][np];
            s1 += gp[wv][s][m][np + 1];
          }
        }
        gh[g2 * 2] = s0 * ISCL2;
        gh[g2 * 2 + 1] = s1 * ISCL2;
      }
      float r0_ = sigmoidf_(gi6[0] + gh[0] + bh[0]);
      float r1_ = sigmoidf_(gi6[1] + gh[1] + bh[1]);
      float z0_ = sigmoidf_(gi6[2] + gh[2] + bh[2]);
      float z1_ = sigmoidf_(gi6[3] + gh[3] + bh[3]);
      float n0_ = tanhf_(gi6[4] + r0_ * (gh[4] + bh[4]));
      float n1_ = tanhf_(gi6[5] + r1_ * (gh[5] + bh[5]));
      float h0_ = (1.f - z0_) * n0_ + z0_ * hr0;
      float h1_ = (1.f - z1_) * n1_ + z1_ * hr1;
      hr0 = h0_; hr1 = h1_;
      float s0 = h0_ * SCL, s1 = h1_ * SCL;
      _Float16 h0h = (_Float16)s0, h1h = (_Float16)s1;
      _Float16 h0l = (_Float16)(s0 - (float)h0h), h1l = (_Float16)(s1 - (float)h1h);
      u32x4 rec;
      rec[0] = (unsigned)__builtin_bit_cast(unsigned short, h0h) |
               ((unsigned)__builtin_bit_cast(unsigned short, h1h) << 16);
      rec[1] = (unsigned)__builtin_bit_cast(unsigned short, h0l) |
               ((unsigned)__builtin_bit_cast(unsigned short, h1l) << 16);
      rec[2] = (unsigned)(step + 1);
      rec[3] = 0u;
      u32x4* dst = (u32x4*)hrec + ((size_t)((step + 1) & 1) * 4096 + wid * 64 + tid);
      asm volatile("global_store_dwordx4 %0, %1, off sc0 sc1"
                   :: "v"(dst), "v"(rec) : "memory");
      if (step == 511) {
        ctx[m * D + d0] = h0_;
        ctx[m * D + d0 + 1] = h1_;
      }
    }
    // no third barrier: next step's poll is the dataflow barrier
  }
}

// Stage 3: U = ctx @ W_A^T + b_A  (f32 VALU, BW-bound); scaled hi/lo out
__global__ __launch_bounds__(256) void k_u(
    const float* __restrict__ WA, const float* __restrict__ bA,
    const float* __restrict__ ctx, _Float16* __restrict__ Uth,
    _Float16* __restrict__ Utl)
{
  __shared__ float As[128 * 32];
  __shared__ float cx[8][1032];
  int tid = threadIdx.x;
  int RB = blockIdx.x;  // 2048 blocks x 128 rows
#pragma unroll
  for (int jj = 0; jj < 8; ++jj) {
    int e = tid * 32 + jj * 4;
    *(f32x4*)&cx[e >> 10][e & 1023] = *(const f32x4*)(ctx + e);
  }
  float acc[4] = {0.f, 0.f, 0.f, 0.f};
  int b = tid & 7, rq = tid >> 3;
  float* AsW = As + (tid >> 6) * 256;  // wave-uniform staging base (1KB)
  int sr = tid >> 3;
  int sc = (tid & 7) * 4;
  __syncthreads();
  for (int kc = 0; kc < 32; ++kc) {
    __syncthreads();
    const float* gsrc = WA + ((size_t)(RB * 128 + sr)) * D + kc * 32 + sc;
    GLDS16(gsrc, AsW);
    GLDS16(gsrc + 32 * D, AsW + 1024);
    GLDS16(gsrc + 64 * D, AsW + 2048);
    GLDS16(gsrc + 96 * D, AsW + 3072);
    __syncthreads();
    f32x4 cxr[8];
#pragma unroll
    for (int kk = 0; kk < 8; ++kk) cxr[kk] = *(const f32x4*)&cx[b][kc * 32 + kk * 4];
#pragma unroll
    for (int r = 0; r < 4; ++r) {
      const float* ap = As + (rq * 4 + r) * 32;
      float s = 0.f;
#pragma unroll
      for (int kk = 0; kk < 8; ++kk) {
        f32x4 a = *(const f32x4*)(ap + kk * 4);
        f32x4 c = cxr[kk];
        s += a[0] * c[0] + a[1] * c[1] + a[2] * c[2] + a[3] * c[3];
      }
      acc[r] += s;
    }
  }
#pragma unroll
  for (int r = 0; r < 4; ++r) {
    int R = RB * 128 + rq * 4 + r;
    float v = (acc[r] + bA[R]) * SCL;
    int n_u = R >> 8, k_u = R & 255;
    _Float16 hi = (_Float16)v;
    size_t o = ((size_t)(b * 256 + k_u)) * NU + n_u;  // k-major for stage-4 frags
    Uth[o] = hi;
    Utl[o] = (_Float16)(v - (float)hi);
  }
}

// Stage 4 v6: occupancy-focused split. 8 waves = (bq: 4 batch-pairs) x (wk: 2
// k-slices); kg loop 0..7 (k = kg*32 + wk*16 + nl). acc[2][8] = 64 VGPRs,
// A-frags chunked 2x4 (32 live), B up-front (16). launch_bounds(512,2) caps
// VGPR at 128 -> 2 blocks/CU, 4 waves/SIMD: Ut L3 load latency finally hidden.
__global__ __launch_bounds__(512, 2) void k_logits(
    const float* __restrict__ eg, const _Float16* __restrict__ Uth,
    const _Float16* __restrict__ Utl, float* __restrict__ out)
{
  __shared__ _Float16 Ash[128 * 40];  // 128 v-rows x 32 n (padded)
  __shared__ _Float16 Asl[128 * 40];
  __shared__ float lacc[8][128];
  int tid = threadIdx.x;
  int v0 = blockIdx.x * 128;
  int lane = tid & 63, w = tid >> 6, nl = lane & 15, q = lane >> 4;
  int bq = w & 3, wk = w >> 2;   // batch pair (2 b each), k-slice (2 of 16)
  for (int i = tid; i < 1024; i += 512) ((float*)lacc)[i] = 0.f;
  int sr = tid >> 2;          // 0..127 staged v-row
  int sc = (tid & 3) * 8;     // n offset
  int vr = v0 + sr;
  if (vr >= NV) vr = NV - 1;
  const float* asrc = eg + (size_t)vr * NU;
  f32x4 zero = {0, 0, 0, 0};
  __syncthreads();
  for (int kg = 0; kg < 8; ++kg) {
    f32x4 acc[2][8];  // [b'][mt] -- 64 VGPRs
#pragma unroll
    for (int b = 0; b < 2; ++b)
#pragma unroll
      for (int mt = 0; mt < 8; ++mt) acc[b][mt] = zero;
    for (int nc = 0; nc < 32; ++nc) {
      __syncthreads();
      {
        const f32x4* p = (const f32x4*)(asrc + nc * 32 + sc);
        f32x4 u0 = p[0];
        f32x4 u1 = p[1];
        half8 h, l;
#pragma unroll
        for (int j = 0; j < 4; ++j) {
          float s0 = u0[j] * SCL;
          _Float16 h0 = (_Float16)s0;
          h[j] = h0; l[j] = (_Float16)(s0 - (float)h0);
          float s1 = u1[j] * SCL;
          _Float16 h1 = (_Float16)s1;
          h[j + 4] = h1; l[j + 4] = (_Float16)(s1 - (float)h1);
        }
        *(half8*)(Ash + sr * 40 + sc) = h;
        *(half8*)(Asl + sr * 40 + sc) = l;
      }
      __syncthreads();
      // B-frags for this wave's 2 batches, up-front (16 regs)
      half8 bfh0, bfl0, bfh1, bfl1;
      {
        int bb0 = bq * 2;
        size_t o0 = ((size_t)(bb0 * 256 + kg * 32 + wk * 16 + nl)) * NU + nc * 32 + q * 8;
        size_t o1 = o0 + (size_t)256 * NU;
        bfh0 = *(const half8*)(Uth + o0);
        bfl0 = *(const half8*)(Utl + o0);
        bfh1 = *(const half8*)(Uth + o1);
        bfl1 = *(const half8*)(Utl + o1);
      }
      __builtin_amdgcn_s_setprio(1);
#pragma unroll
      for (int c = 0; c < 2; ++c) {
        half8 afh[4], afl[4];
#pragma unroll
        for (int mt = 0; mt < 4; ++mt) {
          int row = (c * 4 + mt) * 16 + nl;
          afh[mt] = *(const half8*)(Ash + row * 40 + q * 8);
          afl[mt] = *(const half8*)(Asl + row * 40 + q * 8);
        }
#pragma unroll
        for (int mt = 0; mt < 4; ++mt) {
          int g = c * 4 + mt;
          acc[0][g] = __builtin_amdgcn_mfma_f32_16x16x32_f16(afh[mt], bfh0, acc[0][g], 0, 0, 0);
          acc[0][g] = __builtin_amdgcn_mfma_f32_16x16x32_f16(afh[mt], bfl0, acc[0][g], 0, 0, 0);
          acc[0][g] = __builtin_amdgcn_mfma_f32_16x16x32_f16(afl[mt], bfh0, acc[0][g], 0, 0, 0);
          acc[1][g] = __builtin_amdgcn_mfma_f32_16x16x32_f16(afh[mt], bfh1, acc[1][g], 0, 0, 0);
          acc[1][g] = __builtin_amdgcn_mfma_f32_16x16x32_f16(afh[mt], bfl1, acc[1][g], 0, 0, 0);
          acc[1][g] = __builtin_amdgcn_mfma_f32_16x16x32_f16(afl[mt], bfh1, acc[1][g], 0, 0, 0);
        }
      }
      __builtin_amdgcn_s_setprio(0);
    }
#pragma unroll
    for (int b = 0; b < 2; ++b) {
      int bb = bq * 2 + b;
#pragma unroll
      for (int mt = 0; mt < 8; ++mt) {
#pragma unroll
        for (int i = 0; i < 4; ++i) {
          float s = acc[b][mt][i] * acc[b][mt][i];
          s += __shfl_xor(s, 1);
          s += __shfl_xor(s, 2);
          s += __shfl_xor(s, 4);
          s += __shfl_xor(s, 8);
          if (nl == 0) atomicAdd(&lacc[bb][mt * 16 + q * 4 + i], s);
        }
      }
    }
  }
  __syncthreads();
  if (tid < 128) {
    int v = v0 + tid;
    if (v < NV) {
#pragma unroll
      for (int b = 0; b < 8; ++b) out[(size_t)b * NV + v] = lacc[b][tid] * ISCL4;
    }
  }
}

extern "C" void kernel_launch(void* const* d_in, const int* in_sizes, int n_in,
                              void* d_out, int out_size, void* d_ws, size_t ws_size,
                              hipStream_t stream)
{
  (void)in_sizes; (void)n_in; (void)out_size; (void)ws_size;
  const int* ids = (const int*)d_in[0];
  const float* emb = (const float*)d_in[1];
  const float* Wih = (const float*)d_in[2];
  const float* Whh = (const float*)d_in[3];
  const float* bih = (const float*)d_in[4];
  const float* bhh = (const float*)d_in[5];
  const float* WA = (const float*)d_in[6];
  const float* bA = (const float*)d_in[7];
  const float* eg = (const float*)d_in[8];
  float* out = (float*)d_out;

  char* ws = (char*)d_ws;
  size_t off = 0;
  auto take = [&](size_t bytes) -> char* {
    char* p = ws + off;
    off += (bytes + 255) & ~(size_t)255;
    return p;
  };
  float* gi32 = (float*)take((size_t)4096 * 3072 * 4);        // 50.3 MB
  char* xregion = take((size_t)4096 * 1024 * 2 * 2);          // x hi+lo 16.8 MB
  _Float16* xh = (_Float16*)xregion;
  _Float16* xl = xh + (size_t)4096 * 1024;
  _Float16* wh = (_Float16*)take((size_t)3072 * 1024 * 2);
  _Float16* wl = (_Float16*)take((size_t)3072 * 1024 * 2);
  unsigned* hrec = (unsigned*)take((size_t)2 * 4096 * 16);    // h record dbuf 128KB
  float* ctx = (float*)take((size_t)8 * 1024 * 4);
  // Ut aliases the x region (x dead after k_gi; Ut written by k_u afterwards)
  _Float16* Uth = (_Float16*)xregion;
  _Float16* Utl = Uth + (size_t)8 * 256 * 1024;

  k_prep<<<dim3(7168), dim3(256), 0, stream>>>(ids, emb, Wih, xh, xl, wh, wl);
  k_gi<<<dim3(32, 24), dim3(256), 0, stream>>>(xh, xl, wh, wl, bih, gi32);
  k_init<<<dim3(1), dim3(256), 0, stream>>>(hrec);
  k_gru<<<dim3(64), dim3(384), 0, stream>>>(Whh, gi32, bhh, hrec, ctx);
  k_u<<<dim3(2048), dim3(256), 0, stream>>>(WA, bA, ctx, Uth, Utl);
  k_logits<<<dim3(393), dim3(512), 0, stream>>>(eg, Uth, Utl, out);
}